// Round 2
// baseline (539.078 us; speedup 1.0000x reference)
//
#include <hip/hip_runtime.h>
#include <math.h>

typedef float f32x4 __attribute__((ext_vector_type(4)));

#define NTOK 4096   // H*W
#define CD   512    // C
#define DD   64     // D
#define BQ   64     // query tile
#define BK   64     // key tile
#define LSTR 68     // padded LDS row stride (floats): 68%32==4 -> bank spread, 16B-aligned rows

// ---------------------------------------------------------------------------
// Kernel 1: fused QKV projection. q/k/v[row,d] = relu(x[row,:] @ W + b)
// One wave handles 4 rows; lane = output dim d (64 lanes == D).
// W reads are coalesced 256B/wave; x reads are wave-uniform (L1 broadcast).
// ---------------------------------------------------------------------------
__global__ __launch_bounds__(256) void qkv_kernel(
    const float* __restrict__ x,
    const float* __restrict__ Wq, const float* __restrict__ bq,
    const float* __restrict__ Wk, const float* __restrict__ bk,
    const float* __restrict__ Wv, const float* __restrict__ bv,
    float* __restrict__ q, float* __restrict__ k, float* __restrict__ v)
{
    const int wave = threadIdx.x >> 6;
    const int lane = threadIdx.x & 63;
    int r0 = (blockIdx.x * 4 + wave) * 4;
    r0 = __builtin_amdgcn_readfirstlane(r0);

    float aq[4] = {0.f,0.f,0.f,0.f};
    float ak[4] = {0.f,0.f,0.f,0.f};
    float av[4] = {0.f,0.f,0.f,0.f};

    #pragma unroll 4
    for (int c = 0; c < CD; ++c) {
        const float wqv = Wq[c*DD + lane];
        const float wkv = Wk[c*DD + lane];
        const float wvv = Wv[c*DD + lane];
        #pragma unroll
        for (int r = 0; r < 4; ++r) {
            const float xc = x[(size_t)(r0 + r)*CD + c];
            aq[r] = fmaf(xc, wqv, aq[r]);
            ak[r] = fmaf(xc, wkv, ak[r]);
            av[r] = fmaf(xc, wvv, av[r]);
        }
    }
    const float bqv = bq[lane], bkv = bk[lane], bvv = bv[lane];
    #pragma unroll
    for (int r = 0; r < 4; ++r) {
        q[(size_t)(r0+r)*DD + lane] = fmaxf(aq[r] + bqv, 0.f);
        k[(size_t)(r0+r)*DD + lane] = fmaxf(ak[r] + bkv, 0.f);
        v[(size_t)(r0+r)*DD + lane] = fmaxf(av[r] + bvv, 0.f);
    }
}

// ---------------------------------------------------------------------------
// Kernel 2: flash attention, fp32, online softmax over keys.
// Grid (N/BQ, B); 256 threads; per-thread 4x4 register tiles.
// Thread map: tr=tid/16, tc=tid%16. S rows = tr+16a, S key-cols = tc+16b
// (stride-16 mapping -> padded-stride LDS reads are <=2-way conflicts = free).
// P tile aliases the K tile (K dead after S compute). vs is unpadded
// (PV reads vs[j][4tc..] -> 2-way, free).
// ---------------------------------------------------------------------------
__global__ __launch_bounds__(256) void attn_kernel(
    const float* __restrict__ q, const float* __restrict__ k,
    const float* __restrict__ v, float* __restrict__ o)
{
    __shared__ __align__(16) float qs [BQ * LSTR];
    __shared__ __align__(16) float kps[BK * LSTR];  // K tile, aliased as P tile
    __shared__ __align__(16) float vs [BK * DD];
    __shared__ float red_m[BQ], red_l[BQ], red_a[BQ];

    const int tid = threadIdx.x;
    const int b   = blockIdx.y;
    const int qb  = blockIdx.x;
    const int tr  = tid >> 4;   // 0..15
    const int tc  = tid & 15;   // 0..15

    // stage Q tile once
    const float* qg = q + ((size_t)b*NTOK + qb*BQ)*DD;
    for (int i = tid; i < BQ*16; i += 256) {
        const int r = i >> 4, c4 = (i & 15) * 4;
        *(f32x4*)&qs[r*LSTR + c4] = *(const f32x4*)&qg[(size_t)r*DD + c4];
    }
    if (tid < BQ) { red_m[tid] = -INFINITY; red_l[tid] = 0.f; }

    float acc[4][4];
    #pragma unroll
    for (int a = 0; a < 4; ++a)
        #pragma unroll
        for (int bb = 0; bb < 4; ++bb) acc[a][bb] = 0.f;

    const float* kg = k + (size_t)b*NTOK*DD;
    const float* vg = v + (size_t)b*NTOK*DD;

    for (int t = 0; t < NTOK/BK; ++t) {
        __syncthreads();  // prev PV done before overwriting kps/vs
        const float* kt = kg + (size_t)t*BK*DD;
        const float* vt = vg + (size_t)t*BK*DD;
        for (int i = tid; i < BK*16; i += 256) {
            const int r = i >> 4, c4 = (i & 15) * 4;
            *(f32x4*)&kps[r*LSTR + c4] = *(const f32x4*)&kt[(size_t)r*DD + c4];
            *(f32x4*)&vs [r*DD   + c4] = *(const f32x4*)&vt[(size_t)r*DD + c4];
        }
        __syncthreads();

        // ---- S = Q Kt^T (4x4 per thread, in registers) ----
        float s[4][4];
        #pragma unroll
        for (int a = 0; a < 4; ++a)
            #pragma unroll
            for (int bb = 0; bb < 4; ++bb) s[a][bb] = 0.f;

        #pragma unroll 4
        for (int d0 = 0; d0 < 16; ++d0) {
            f32x4 q4[4], k4[4];
            #pragma unroll
            for (int a = 0; a < 4; ++a)
                q4[a] = *(const f32x4*)&qs[(tr + 16*a)*LSTR + d0*4];
            #pragma unroll
            for (int bb = 0; bb < 4; ++bb)
                k4[bb] = *(const f32x4*)&kps[(tc + 16*bb)*LSTR + d0*4];
            #pragma unroll
            for (int a = 0; a < 4; ++a)
                #pragma unroll
                for (int bb = 0; bb < 4; ++bb) {
                    s[a][bb] = fmaf(q4[a][0], k4[bb][0], s[a][bb]);
                    s[a][bb] = fmaf(q4[a][1], k4[bb][1], s[a][bb]);
                    s[a][bb] = fmaf(q4[a][2], k4[bb][2], s[a][bb]);
                    s[a][bb] = fmaf(q4[a][3], k4[bb][3], s[a][bb]);
                }
        }
        __syncthreads();  // everyone done reading K before P overwrites it

        #pragma unroll
        for (int a = 0; a < 4; ++a)
            #pragma unroll
            for (int bb = 0; bb < 4; ++bb)
                kps[(tr + 16*a)*LSTR + tc + 16*bb] = s[a][bb];
        __syncthreads();

        // ---- online softmax: 4 threads per row ----
        {
            const int row = tid >> 2, part = tid & 3;
            float* pr = &kps[row*LSTR + part*16];
            f32x4 pv[4];
            #pragma unroll
            for (int i = 0; i < 4; ++i) pv[i] = *(const f32x4*)&pr[i*4];
            float mx = -INFINITY;
            #pragma unroll
            for (int i = 0; i < 4; ++i)
                #pragma unroll
                for (int e = 0; e < 4; ++e) mx = fmaxf(mx, pv[i][e]);
            mx = fmaxf(mx, __shfl_xor(mx, 1));
            mx = fmaxf(mx, __shfl_xor(mx, 2));
            const float m_old = red_m[row];
            const float m_new = fmaxf(m_old, mx);
            float sum = 0.f;
            #pragma unroll
            for (int i = 0; i < 4; ++i) {
                #pragma unroll
                for (int e = 0; e < 4; ++e) {
                    const float p = __expf(pv[i][e] - m_new);
                    pv[i][e] = p;
                    sum += p;
                }
                *(f32x4*)&pr[i*4] = pv[i];
            }
            sum += __shfl_xor(sum, 1);
            sum += __shfl_xor(sum, 2);
            if (part == 0) {
                const float alpha = __expf(m_old - m_new);
                red_a[row] = alpha;
                red_m[row] = m_new;
                red_l[row] = fmaf(red_l[row], alpha, sum);
            }
        }
        __syncthreads();

        // ---- PV: acc = acc*alpha + P @ V ; out cols = 4*tc..4*tc+3 ----
        float al[4];
        #pragma unroll
        for (int a = 0; a < 4; ++a) al[a] = red_a[tr + 16*a];
        #pragma unroll
        for (int a = 0; a < 4; ++a)
            #pragma unroll
            for (int bb = 0; bb < 4; ++bb) acc[a][bb] *= al[a];

        #pragma unroll 2
        for (int j0 = 0; j0 < 16; ++j0) {
            f32x4 p4[4], v4[4];
            #pragma unroll
            for (int a = 0; a < 4; ++a)
                p4[a] = *(const f32x4*)&kps[(tr + 16*a)*LSTR + j0*4];
            #pragma unroll
            for (int jj = 0; jj < 4; ++jj)
                v4[jj] = *(const f32x4*)&vs[(j0*4 + jj)*DD + tc*4];
            #pragma unroll
            for (int a = 0; a < 4; ++a)
                #pragma unroll
                for (int jj = 0; jj < 4; ++jj) {
                    const float p = p4[a][jj];
                    #pragma unroll
                    for (int bb = 0; bb < 4; ++bb)
                        acc[a][bb] = fmaf(p, v4[jj][bb], acc[a][bb]);
                }
        }
    }

    // epilogue: normalize and write (red_l stable since pre-PV barrier)
    float* og = o + ((size_t)b*NTOK + qb*BQ)*DD;
    #pragma unroll
    for (int a = 0; a < 4; ++a) {
        const int ra = tr + 16*a;
        const float inv = 1.0f / red_l[ra];
        f32x4 out4;
        #pragma unroll
        for (int bb = 0; bb < 4; ++bb) out4[bb] = acc[a][bb] * inv;
        *(f32x4*)&og[(size_t)ra*DD + tc*4] = out4;
    }
}

// ---------------------------------------------------------------------------
// Kernel 3: output projection. out[row,c] = relu(o[row,:] @ Wo + bo)
// One wave per row; lane covers 8 columns of 512.
// ---------------------------------------------------------------------------
__global__ __launch_bounds__(256) void oproj_kernel(
    const float* __restrict__ o, const float* __restrict__ Wo,
    const float* __restrict__ bo, float* __restrict__ out)
{
    const int wave = threadIdx.x >> 6;
    const int lane = threadIdx.x & 63;
    int row = blockIdx.x * 4 + wave;
    row = __builtin_amdgcn_readfirstlane(row);
    const float* orow = o + (size_t)row * DD;

    float acc[8] = {0.f,0.f,0.f,0.f,0.f,0.f,0.f,0.f};
    #pragma unroll 4
    for (int d = 0; d < DD; ++d) {
        const float od = orow[d];
        #pragma unroll
        for (int j = 0; j < 8; ++j)
            acc[j] = fmaf(od, Wo[(size_t)d*CD + j*64 + lane], acc[j]);
    }
    #pragma unroll
    for (int j = 0; j < 8; ++j)
        out[(size_t)row*CD + j*64 + lane] = fmaxf(acc[j] + bo[j*64 + lane], 0.f);
}

// ---------------------------------------------------------------------------
extern "C" void kernel_launch(void* const* d_in, const int* in_sizes, int n_in,
                              void* d_out, int out_size, void* d_ws, size_t ws_size,
                              hipStream_t stream) {
    const float* x  = (const float*)d_in[0];
    const float* Wq = (const float*)d_in[1];
    const float* bq = (const float*)d_in[2];
    const float* Wk = (const float*)d_in[3];
    const float* bk = (const float*)d_in[4];
    const float* Wv = (const float*)d_in[5];
    const float* bv = (const float*)d_in[6];
    const float* Wo = (const float*)d_in[7];
    const float* bo = (const float*)d_in[8];
    float* out = (float*)d_out;

    // workspace: q,k,v,o fp32, each B*N*D = 4*4096*64 = 1M floats (16 MB total)
    float* ws = (float*)d_ws;
    const size_t SEG = (size_t)4 * NTOK * DD;  // 1048576
    float* q = ws;
    float* k = ws + SEG;
    float* v = ws + 2*SEG;
    float* o = ws + 3*SEG;

    // 16384 rows total
    qkv_kernel<<<1024, 256, 0, stream>>>(x, Wq, bq, Wk, bk, Wv, bv, q, k, v);
    attn_kernel<<<dim3(NTOK/BQ, 4), 256, 0, stream>>>(q, k, v, o);
    oproj_kernel<<<4096, 256, 0, stream>>>(o, Wo, bo, out);
}

// Round 5
// 328.512 us; speedup vs baseline: 1.6410x; 1.6410x over previous
//
#include <hip/hip_runtime.h>
#include <math.h>

typedef float  f32x4  __attribute__((ext_vector_type(4)));
typedef __bf16 bf16x8 __attribute__((ext_vector_type(8)));

#define NTOK 4096   // H*W
#define CD   512    // C
#define DD   64     // D
#define BQ   64     // query tile (4 waves x 16 rows)
#define BK   64     // key tile
#define KSTR 72     // LDS row stride in bf16 elems: 144B -> balanced banks for b128 frag reads

#define MFMA(a, b, c) __builtin_amdgcn_mfma_f32_16x16x32_bf16((a), (b), (c), 0, 0, 0)

static __device__ __forceinline__ unsigned short f2bf(float f) {
    union { float f; unsigned int u; } a; a.f = f;
    unsigned int r = a.u + 0x7fffu + ((a.u >> 16) & 1u);  // RNE; inputs finite here
    return (unsigned short)(r >> 16);
}
static __device__ __forceinline__ float bf2f(unsigned short h) {
    union { unsigned int u; float f; } a; a.u = ((unsigned int)h) << 16;
    return a.f;
}

// ---------------------------------------------------------------------------
// Kernel 1: fused QKV projection, fp32 accumulate; outputs q,k as split bf16
// (hi+lo) and v as bf16. One wave = 4 rows; lane = output dim d (64 == D).
// ---------------------------------------------------------------------------
__global__ __launch_bounds__(256) void qkv_kernel(
    const float* __restrict__ x,
    const float* __restrict__ Wq, const float* __restrict__ bq,
    const float* __restrict__ Wk, const float* __restrict__ bk,
    const float* __restrict__ Wv, const float* __restrict__ bv,
    unsigned short* __restrict__ qh, unsigned short* __restrict__ qlo,
    unsigned short* __restrict__ kh, unsigned short* __restrict__ klo,
    unsigned short* __restrict__ vb)
{
    const int wave = threadIdx.x >> 6;
    const int lane = threadIdx.x & 63;
    int r0 = (blockIdx.x * 4 + wave) * 4;
    r0 = __builtin_amdgcn_readfirstlane(r0);

    float aq[4] = {0.f,0.f,0.f,0.f};
    float ak[4] = {0.f,0.f,0.f,0.f};
    float av[4] = {0.f,0.f,0.f,0.f};

    #pragma unroll 4
    for (int c = 0; c < CD; ++c) {
        const float wqv = Wq[c*DD + lane];
        const float wkv = Wk[c*DD + lane];
        const float wvv = Wv[c*DD + lane];
        #pragma unroll
        for (int r = 0; r < 4; ++r) {
            const float xc = x[(size_t)(r0 + r)*CD + c];
            aq[r] = fmaf(xc, wqv, aq[r]);
            ak[r] = fmaf(xc, wkv, ak[r]);
            av[r] = fmaf(xc, wvv, av[r]);
        }
    }
    const float bqv = bq[lane], bkv = bk[lane], bvv = bv[lane];
    #pragma unroll
    for (int r = 0; r < 4; ++r) {
        const size_t idx = (size_t)(r0+r)*DD + lane;
        float qv = fmaxf(aq[r] + bqv, 0.f);
        unsigned short h = f2bf(qv);
        qh[idx]  = h;
        qlo[idx] = f2bf(qv - bf2f(h));
        float kv = fmaxf(ak[r] + bkv, 0.f);
        h = f2bf(kv);
        kh[idx]  = h;
        klo[idx] = f2bf(kv - bf2f(h));
        vb[idx]  = f2bf(fmaxf(av[r] + bvv, 0.f));
    }
}

// ---------------------------------------------------------------------------
// Kernel 2: flash attention, bf16 MFMA core.
// Grid (N/BQ, B), 256 thr = 4 waves; wave w owns q-rows [16w,16w+16).
// QK^T: split-bf16 x3 MFMA (near-fp32 scores). Softmax fp32 in registers
// (lane owns rows 4*l4+r per C/D layout). PV: bf16 P (via LDS, wave-private
// region) x bf16 V (staged transposed).
// ---------------------------------------------------------------------------
__global__ __launch_bounds__(256) void attn_kernel(
    const unsigned short* __restrict__ qh, const unsigned short* __restrict__ qlo,
    const unsigned short* __restrict__ kh, const unsigned short* __restrict__ klo,
    const unsigned short* __restrict__ vb, float* __restrict__ o)
{
    __shared__ __align__(16) unsigned short kh_s[BK*KSTR];
    __shared__ __align__(16) unsigned short kl_s[BK*KSTR];
    __shared__ __align__(16) unsigned short vt_s[DD*KSTR];  // V transposed [d][key]
    __shared__ __align__(16) unsigned short p_s [BQ*KSTR];  // P, wave-private rows

    const int tid  = threadIdx.x;
    const int w    = tid >> 6;
    const int lane = tid & 63;
    const int l15  = lane & 15;
    const int l4   = lane >> 4;
    const int b    = blockIdx.y;
    const int qb   = blockIdx.x;

    // Q fragments direct from global: lane reads q[16w+l15][8*l4+32s .. +8]
    const size_t qrow = ((size_t)b*NTOK + (size_t)qb*BQ + 16*w + l15)*DD;
    bf16x8 qhf[2], qlf[2];
    qhf[0] = *(const bf16x8*)&qh [qrow + 8*l4];
    qhf[1] = *(const bf16x8*)&qh [qrow + 8*l4 + 32];
    qlf[0] = *(const bf16x8*)&qlo[qrow + 8*l4];
    qlf[1] = *(const bf16x8*)&qlo[qrow + 8*l4 + 32];

    f32x4 acc[4];
    #pragma unroll
    for (int nt = 0; nt < 4; ++nt) acc[nt] = (f32x4){0.f,0.f,0.f,0.f};
    float m_run[4] = {-INFINITY,-INFINITY,-INFINITY,-INFINITY};
    float l_run[4] = {0.f,0.f,0.f,0.f};

    // staging map: thread t covers key=t>>2, 16 d-cols starting (t&3)*16
    const int skey = tid >> 2;
    const int sc   = (tid & 3) * 16;
    const size_t kvb0 = (size_t)b*NTOK*DD;

    for (int t = 0; t < NTOK/BK; ++t) {
        __syncthreads();   // prior tile's K/V reads complete before overwrite
        const size_t kb = kvb0 + (size_t)t*BK*DD + (size_t)skey*DD + sc;
        *(bf16x8*)&kh_s[skey*KSTR + sc]     = *(const bf16x8*)&kh [kb];
        *(bf16x8*)&kh_s[skey*KSTR + sc + 8] = *(const bf16x8*)&kh [kb + 8];
        *(bf16x8*)&kl_s[skey*KSTR + sc]     = *(const bf16x8*)&klo[kb];
        *(bf16x8*)&kl_s[skey*KSTR + sc + 8] = *(const bf16x8*)&klo[kb + 8];
        bf16x8 v0 = *(const bf16x8*)&vb[kb];
        bf16x8 v1 = *(const bf16x8*)&vb[kb + 8];
        #pragma unroll
        for (int i = 0; i < 8; ++i) {
            *(__bf16*)&vt_s[(sc + i    )*KSTR + skey] = v0[i];
            *(__bf16*)&vt_s[(sc + 8 + i)*KSTR + skey] = v1[i];
        }
        __syncthreads();

        // ---- S = Q K^T, split-bf16 x3; lane holds S[4*l4+r][16nt+l15] ----
        f32x4 sv[4];
        #pragma unroll
        for (int nt = 0; nt < 4; ++nt) sv[nt] = (f32x4){0.f,0.f,0.f,0.f};
        #pragma unroll
        for (int nt = 0; nt < 4; ++nt) {
            #pragma unroll
            for (int s = 0; s < 2; ++s) {
                const int off = (16*nt + l15)*KSTR + 8*l4 + 32*s;
                bf16x8 khf = *(const bf16x8*)&kh_s[off];
                bf16x8 klf = *(const bf16x8*)&kl_s[off];
                sv[nt] = MFMA(qhf[s], khf, sv[nt]);
                sv[nt] = MFMA(qhf[s], klf, sv[nt]);
                sv[nt] = MFMA(qlf[s], khf, sv[nt]);
            }
        }

        // ---- online softmax, fp32 in registers ----
        float mnew[4], alpha[4], ssum[4];
        #pragma unroll
        for (int r = 0; r < 4; ++r) {
            float mr = fmaxf(fmaxf(sv[0][r], sv[1][r]), fmaxf(sv[2][r], sv[3][r]));
            mr = fmaxf(mr, __shfl_xor(mr, 1));
            mr = fmaxf(mr, __shfl_xor(mr, 2));
            mr = fmaxf(mr, __shfl_xor(mr, 4));
            mr = fmaxf(mr, __shfl_xor(mr, 8));
            mnew[r]  = fmaxf(m_run[r], mr);
            alpha[r] = __expf(m_run[r] - mnew[r]);
            m_run[r] = mnew[r];
            ssum[r]  = 0.f;
        }
        #pragma unroll
        for (int nt = 0; nt < 4; ++nt)
            #pragma unroll
            for (int r = 0; r < 4; ++r) {
                const float p = __expf(sv[nt][r] - mnew[r]);
                sv[nt][r] = p;
                ssum[r] += p;
            }
        #pragma unroll
        for (int r = 0; r < 4; ++r) {
            float s = ssum[r];
            s += __shfl_xor(s, 1);
            s += __shfl_xor(s, 2);
            s += __shfl_xor(s, 4);
            s += __shfl_xor(s, 8);
            l_run[r] = l_run[r]*alpha[r] + s;
        }

        // ---- P -> LDS (bf16), wave-private rows; rescale acc ----
        #pragma unroll
        for (int nt = 0; nt < 4; ++nt)
            #pragma unroll
            for (int r = 0; r < 4; ++r)
                p_s[(16*w + 4*l4 + r)*KSTR + 16*nt + l15] = f2bf(sv[nt][r]);
        #pragma unroll
        for (int nt = 0; nt < 4; ++nt)
            #pragma unroll
            for (int r = 0; r < 4; ++r)
                acc[nt][r] *= alpha[r];

        // ---- PV: acc += P @ V (bf16). Same-wave LDS dep -> lgkmcnt only ----
        bf16x8 paf[2];
        paf[0] = *(const bf16x8*)&p_s[(16*w + l15)*KSTR + 8*l4];
        paf[1] = *(const bf16x8*)&p_s[(16*w + l15)*KSTR + 8*l4 + 32];
        #pragma unroll
        for (int nt = 0; nt < 4; ++nt) {
            #pragma unroll
            for (int s = 0; s < 2; ++s) {
                bf16x8 vf = *(const bf16x8*)&vt_s[(16*nt + l15)*KSTR + 8*l4 + 32*s];
                acc[nt] = MFMA(paf[s], vf, acc[nt]);
            }
        }
    }

    // epilogue: normalize, write fp32 o
    const size_t ob = ((size_t)b*NTOK + (size_t)qb*BQ + 16*w)*DD;
    #pragma unroll
    for (int r = 0; r < 4; ++r) {
        const float inv = 1.0f / l_run[r];
        #pragma unroll
        for (int nt = 0; nt < 4; ++nt)
            o[ob + (size_t)(4*l4 + r)*DD + 16*nt + l15] = acc[nt][r] * inv;
    }
}

// ---------------------------------------------------------------------------
// Kernel 3: output projection (fp32). One wave per row; lane covers 8 cols.
// ---------------------------------------------------------------------------
__global__ __launch_bounds__(256) void oproj_kernel(
    const float* __restrict__ o, const float* __restrict__ Wo,
    const float* __restrict__ bo, float* __restrict__ out)
{
    const int wave = threadIdx.x >> 6;
    const int lane = threadIdx.x & 63;
    int row = blockIdx.x * 4 + wave;
    row = __builtin_amdgcn_readfirstlane(row);
    const float* orow = o + (size_t)row * DD;

    float acc[8] = {0.f,0.f,0.f,0.f,0.f,0.f,0.f,0.f};
    #pragma unroll 4
    for (int d = 0; d < DD; ++d) {
        const float od = orow[d];
        #pragma unroll
        for (int j = 0; j < 8; ++j)
            acc[j] = fmaf(od, Wo[(size_t)d*CD + j*64 + lane], acc[j]);
    }
    #pragma unroll
    for (int j = 0; j < 8; ++j)
        out[(size_t)row*CD + j*64 + lane] = fmaxf(acc[j] + bo[j*64 + lane], 0.f);
}

// ---------------------------------------------------------------------------
extern "C" void kernel_launch(void* const* d_in, const int* in_sizes, int n_in,
                              void* d_out, int out_size, void* d_ws, size_t ws_size,
                              hipStream_t stream) {
    const float* x  = (const float*)d_in[0];
    const float* Wq = (const float*)d_in[1];
    const float* bq = (const float*)d_in[2];
    const float* Wk = (const float*)d_in[3];
    const float* bk = (const float*)d_in[4];
    const float* Wv = (const float*)d_in[5];
    const float* bv = (const float*)d_in[6];
    const float* Wo = (const float*)d_in[7];
    const float* bo = (const float*)d_in[8];
    float* out = (float*)d_out;

    // workspace: 5 bf16 arrays (qh,qlo,kh,klo,vb) of B*N*D = 1M elems (2MB each)
    // + fp32 o (4MB) = 14MB total, all fully rewritten every call.
    unsigned short* u = (unsigned short*)d_ws;
    const size_t SEG = (size_t)4 * NTOK * DD;  // 1048576 elems
    unsigned short* qh  = u;
    unsigned short* qlo = u + SEG;
    unsigned short* kh  = u + 2*SEG;
    unsigned short* klo = u + 3*SEG;
    unsigned short* vb  = u + 4*SEG;
    float* o = (float*)(u + 5*SEG);  // 10MB offset, 16B-aligned

    qkv_kernel<<<1024, 256, 0, stream>>>(x, Wq, bq, Wk, bk, Wv, bv,
                                         qh, qlo, kh, klo, vb);
    attn_kernel<<<dim3(NTOK/BQ, 4), 256, 0, stream>>>(qh, qlo, kh, klo, vb, o);
    oproj_kernel<<<4096, 256, 0, stream>>>(o, Wo, bo, out);
}

// Round 6
// 225.973 us; speedup vs baseline: 2.3856x; 1.4538x over previous
//
#include <hip/hip_runtime.h>
#include <math.h>

typedef float  f32x4  __attribute__((ext_vector_type(4)));
typedef __bf16 bf16x8 __attribute__((ext_vector_type(8)));
typedef __bf16 bf16x4 __attribute__((ext_vector_type(4)));
typedef unsigned short ushort_t;

#define NTOK  4096   // H*W
#define CD    512    // C
#define DD    64     // D
#define BQ    64     // query tile (4 waves x 16 rows)
#define BK    64     // key tile
#define KSTR  72     // LDS row stride (bf16 elems); 144B rows
#define NROWS 16384  // B*NTOK

#define MFMA(a, b, c) __builtin_amdgcn_mfma_f32_16x16x32_bf16((a), (b), (c), 0, 0, 0)

static __device__ __forceinline__ ushort_t f2bf(float f) {
    union { float f; unsigned int u; } a; a.f = f;
    unsigned int r = a.u + 0x7fffu + ((a.u >> 16) & 1u);  // RNE; finite inputs
    return (ushort_t)(r >> 16);
}
static __device__ __forceinline__ float bf2f(ushort_t h) {
    union { unsigned int u; float f; } a; a.u = ((unsigned int)h) << 16;
    return a.f;
}

// ---------------------------------------------------------------------------
// Kernel 1: fused QKV projection (fp32 acc). Outputs q,k split bf16 (hi+lo)
// row-major, and V TRANSPOSED vT[b][d][tok] (bf16) via conflict-free LDS tile
// so the attention inner loop never transposes.
// Block = 256 thr = 4 waves; wave owns 4 rows; lane = d.
// ---------------------------------------------------------------------------
__global__ __launch_bounds__(256) void qkv_kernel(
    const float* __restrict__ x,
    const float* __restrict__ Wq, const float* __restrict__ bq,
    const float* __restrict__ Wk, const float* __restrict__ bk,
    const float* __restrict__ Wv, const float* __restrict__ bv,
    ushort_t* __restrict__ qh, ushort_t* __restrict__ qlo,
    ushort_t* __restrict__ kh, ushort_t* __restrict__ klo,
    ushort_t* __restrict__ vT)
{
    __shared__ __align__(8) ushort_t vtile[DD][20];  // pad 20: write banks 9*d-free, reads 8B-aligned

    const int wave = threadIdx.x >> 6;
    const int lane = threadIdx.x & 63;
    const int r0b  = blockIdx.x * 16;          // block's first global row
    int r0 = r0b + wave * 4;
    r0 = __builtin_amdgcn_readfirstlane(r0);

    float aq[4] = {0.f,0.f,0.f,0.f};
    float ak[4] = {0.f,0.f,0.f,0.f};
    float av[4] = {0.f,0.f,0.f,0.f};

    #pragma unroll 4
    for (int c = 0; c < CD; ++c) {
        const float wqv = Wq[c*DD + lane];
        const float wkv = Wk[c*DD + lane];
        const float wvv = Wv[c*DD + lane];
        #pragma unroll
        for (int r = 0; r < 4; ++r) {
            const float xc = x[(size_t)(r0 + r)*CD + c];
            aq[r] = fmaf(xc, wqv, aq[r]);
            ak[r] = fmaf(xc, wkv, ak[r]);
            av[r] = fmaf(xc, wvv, av[r]);
        }
    }
    const float bqv = bq[lane], bkv = bk[lane], bvv = bv[lane];
    #pragma unroll
    for (int r = 0; r < 4; ++r) {
        const size_t idx = (size_t)(r0+r)*DD + lane;
        float qv = fmaxf(aq[r] + bqv, 0.f);
        ushort_t h = f2bf(qv);
        qh[idx]  = h;
        qlo[idx] = f2bf(qv - bf2f(h));
        float kv = fmaxf(ak[r] + bkv, 0.f);
        h = f2bf(kv);
        kh[idx]  = h;
        klo[idx] = f2bf(kv - bf2f(h));
        vtile[lane][wave*4 + r] = f2bf(fmaxf(av[r] + bvv, 0.f));
    }
    __syncthreads();
    // write vT[b][d][tok]: thread covers (d = tid>>2, 4 tokens at (tid&3)*4)
    const int d  = threadIdx.x >> 2;
    const int j4 = (threadIdx.x & 3) * 4;
    const int bb   = r0b / NTOK;
    const int tok0 = r0b % NTOK;
    bf16x4 v4 = *(const bf16x4*)&vtile[d][j4];
    *(bf16x4*)&vT[((size_t)bb*DD + d)*NTOK + tok0 + j4] = v4;
}

// ---------------------------------------------------------------------------
// Kernel 2: flash attention over a KEY SEGMENT (split-K). Grid (N/BQ, B, nseg).
// 4 waves; wave w owns q-rows [16w,16w+16). QK^T split-bf16 x3 (fp32-grade),
// softmax fp32 in registers, PV bf16. Register prefetch of next tile's
// global loads (issued before compute, consumed after it). Writes partial
// (acc, m, l) per segment; reduce_kernel combines.
// ---------------------------------------------------------------------------
__global__ __launch_bounds__(256) void attn_kernel(
    const ushort_t* __restrict__ qh, const ushort_t* __restrict__ qlo,
    const ushort_t* __restrict__ kh, const ushort_t* __restrict__ klo,
    const ushort_t* __restrict__ vT,
    float* __restrict__ o_part, float* __restrict__ m_part,
    float* __restrict__ l_part, int nseg)
{
    __shared__ __align__(16) ushort_t kh_s[BK*KSTR];
    __shared__ __align__(16) ushort_t kl_s[BK*KSTR];
    __shared__ __align__(16) ushort_t vt_s[DD*KSTR];  // [d][key]
    __shared__ __align__(16) ushort_t p_s [BQ*KSTR];  // wave-private rows

    const int tid  = threadIdx.x;
    const int w    = tid >> 6;
    const int lane = tid & 63;
    const int l15  = lane & 15;
    const int l4   = lane >> 4;
    const int b    = blockIdx.y;
    const int qb   = blockIdx.x;
    const int seg  = blockIdx.z;
    const int kv0  = seg * (NTOK / nseg);
    const int tiles = (NTOK / nseg) / BK;

    // Q fragments from global
    const size_t qrow = ((size_t)b*NTOK + (size_t)qb*BQ + 16*w + l15)*DD;
    bf16x8 qhf[2], qlf[2];
    qhf[0] = *(const bf16x8*)&qh [qrow + 8*l4];
    qhf[1] = *(const bf16x8*)&qh [qrow + 8*l4 + 32];
    qlf[0] = *(const bf16x8*)&qlo[qrow + 8*l4];
    qlf[1] = *(const bf16x8*)&qlo[qrow + 8*l4 + 32];

    f32x4 acc[4];
    #pragma unroll
    for (int nt = 0; nt < 4; ++nt) acc[nt] = (f32x4){0.f,0.f,0.f,0.f};
    float m_run[4] = {-INFINITY,-INFINITY,-INFINITY,-INFINITY};
    float l_run[4] = {0.f,0.f,0.f,0.f};

    // staging map: skey = LDS row (key for K, d for vT), sc = 16-col offset
    const int skey = tid >> 2;
    const int sc   = (tid & 3) * 16;

    bf16x8 rg0, rg1, rg2, rg3, rg4, rg5;
    {   // prologue: tile 0 loads
        const size_t kb = ((size_t)b*NTOK + kv0 + skey)*DD + sc;
        rg0 = *(const bf16x8*)&kh [kb];   rg1 = *(const bf16x8*)&kh [kb + 8];
        rg2 = *(const bf16x8*)&klo[kb];   rg3 = *(const bf16x8*)&klo[kb + 8];
        const size_t vb_ = ((size_t)b*DD + skey)*NTOK + kv0 + sc;
        rg4 = *(const bf16x8*)&vT[vb_];   rg5 = *(const bf16x8*)&vT[vb_ + 8];
    }

    for (int t = 0; t < tiles; ++t) {
        __syncthreads();   // prev tile's LDS reads complete
        *(bf16x8*)&kh_s[skey*KSTR + sc]     = rg0;
        *(bf16x8*)&kh_s[skey*KSTR + sc + 8] = rg1;
        *(bf16x8*)&kl_s[skey*KSTR + sc]     = rg2;
        *(bf16x8*)&kl_s[skey*KSTR + sc + 8] = rg3;
        *(bf16x8*)&vt_s[skey*KSTR + sc]     = rg4;
        *(bf16x8*)&vt_s[skey*KSTR + sc + 8] = rg5;
        if (t + 1 < tiles) {  // prefetch next tile; latency hides under compute
            const size_t kb = ((size_t)b*NTOK + kv0 + (t+1)*BK + skey)*DD + sc;
            rg0 = *(const bf16x8*)&kh [kb];   rg1 = *(const bf16x8*)&kh [kb + 8];
            rg2 = *(const bf16x8*)&klo[kb];   rg3 = *(const bf16x8*)&klo[kb + 8];
            const size_t vb_ = ((size_t)b*DD + skey)*NTOK + kv0 + (t+1)*BK + sc;
            rg4 = *(const bf16x8*)&vT[vb_];   rg5 = *(const bf16x8*)&vT[vb_ + 8];
        }
        __syncthreads();

        // ---- S = Q K^T, split-bf16 x3; lane holds S[4*l4+r][16nt+l15] ----
        f32x4 sv[4];
        #pragma unroll
        for (int nt = 0; nt < 4; ++nt) sv[nt] = (f32x4){0.f,0.f,0.f,0.f};
        #pragma unroll
        for (int nt = 0; nt < 4; ++nt) {
            #pragma unroll
            for (int s = 0; s < 2; ++s) {
                const int off = (16*nt + l15)*KSTR + 8*l4 + 32*s;
                bf16x8 khf = *(const bf16x8*)&kh_s[off];
                bf16x8 klf = *(const bf16x8*)&kl_s[off];
                sv[nt] = MFMA(qhf[s], khf, sv[nt]);
                sv[nt] = MFMA(qhf[s], klf, sv[nt]);
                sv[nt] = MFMA(qlf[s], khf, sv[nt]);
            }
        }

        // ---- online softmax, fp32 in registers ----
        float mnew[4], alpha[4], ssum[4];
        #pragma unroll
        for (int r = 0; r < 4; ++r) {
            float mr = fmaxf(fmaxf(sv[0][r], sv[1][r]), fmaxf(sv[2][r], sv[3][r]));
            mr = fmaxf(mr, __shfl_xor(mr, 1));
            mr = fmaxf(mr, __shfl_xor(mr, 2));
            mr = fmaxf(mr, __shfl_xor(mr, 4));
            mr = fmaxf(mr, __shfl_xor(mr, 8));
            mnew[r]  = fmaxf(m_run[r], mr);
            alpha[r] = __expf(m_run[r] - mnew[r]);
            m_run[r] = mnew[r];
            ssum[r]  = 0.f;
        }
        #pragma unroll
        for (int nt = 0; nt < 4; ++nt)
            #pragma unroll
            for (int r = 0; r < 4; ++r) {
                const float p = __expf(sv[nt][r] - mnew[r]);
                sv[nt][r] = p;
                ssum[r] += p;
            }
        #pragma unroll
        for (int r = 0; r < 4; ++r) {
            float s = ssum[r];
            s += __shfl_xor(s, 1);
            s += __shfl_xor(s, 2);
            s += __shfl_xor(s, 4);
            s += __shfl_xor(s, 8);
            l_run[r] = l_run[r]*alpha[r] + s;
        }

        // ---- P -> LDS (bf16) wave-private; rescale acc ----
        #pragma unroll
        for (int nt = 0; nt < 4; ++nt)
            #pragma unroll
            for (int r = 0; r < 4; ++r)
                p_s[(16*w + 4*l4 + r)*KSTR + 16*nt + l15] = f2bf(sv[nt][r]);
        #pragma unroll
        for (int nt = 0; nt < 4; ++nt)
            #pragma unroll
            for (int r = 0; r < 4; ++r)
                acc[nt][r] *= alpha[r];

        // ---- PV: acc += P @ V (same-wave LDS dep -> lgkmcnt only) ----
        bf16x8 paf[2];
        paf[0] = *(const bf16x8*)&p_s[(16*w + l15)*KSTR + 8*l4];
        paf[1] = *(const bf16x8*)&p_s[(16*w + l15)*KSTR + 8*l4 + 32];
        #pragma unroll
        for (int nt = 0; nt < 4; ++nt) {
            #pragma unroll
            for (int s = 0; s < 2; ++s) {
                bf16x8 vf = *(const bf16x8*)&vt_s[(16*nt + l15)*KSTR + 8*l4 + 32*s];
                acc[nt] = MFMA(paf[s], vf, acc[nt]);
            }
        }
    }

    // epilogue: write UNNORMALIZED partials + (m,l)
    const size_t prow0 = (size_t)(seg*4 + b)*NTOK + (size_t)qb*BQ + 16*w;
    #pragma unroll
    for (int r = 0; r < 4; ++r) {
        const size_t row = prow0 + 4*l4 + r;
        #pragma unroll
        for (int nt = 0; nt < 4; ++nt)
            o_part[row*DD + 16*nt + l15] = acc[nt][r];
        if (l15 == 0) { m_part[row] = m_run[r]; l_part[row] = l_run[r]; }
    }
}

// ---------------------------------------------------------------------------
// Kernel 2b: combine split-K partials. One wave per row (lane = d).
// o[row][d] = sum_s exp(m_s - m*) acc_s[row][d] / sum_s exp(m_s - m*) l_s
// ---------------------------------------------------------------------------
__global__ __launch_bounds__(256) void reduce_kernel(
    const float* __restrict__ o_part, const float* __restrict__ m_part,
    const float* __restrict__ l_part, float* __restrict__ o, int nseg)
{
    const int gr   = blockIdx.x * 4 + (threadIdx.x >> 6);  // 0..NROWS-1
    const int lane = threadIdx.x & 63;
    float m = -INFINITY;
    for (int s = 0; s < nseg; ++s)
        m = fmaxf(m, m_part[(size_t)s*NROWS + gr]);
    float osum = 0.f, lsum = 0.f;
    for (int s = 0; s < nseg; ++s) {
        const float wgt = __expf(m_part[(size_t)s*NROWS + gr] - m);
        osum = fmaf(wgt, o_part[((size_t)s*NROWS + gr)*DD + lane], osum);
        lsum = fmaf(wgt, l_part[(size_t)s*NROWS + gr], lsum);
    }
    o[(size_t)gr*DD + lane] = osum / lsum;
}

// ---------------------------------------------------------------------------
// Kernel 3: output projection (fp32). One wave per row; lane covers 8 cols.
// ---------------------------------------------------------------------------
__global__ __launch_bounds__(256) void oproj_kernel(
    const float* __restrict__ o, const float* __restrict__ Wo,
    const float* __restrict__ bo, float* __restrict__ out)
{
    const int wave = threadIdx.x >> 6;
    const int lane = threadIdx.x & 63;
    int row = blockIdx.x * 4 + wave;
    row = __builtin_amdgcn_readfirstlane(row);
    const float* orow = o + (size_t)row * DD;

    float acc[8] = {0.f,0.f,0.f,0.f,0.f,0.f,0.f,0.f};
    #pragma unroll 4
    for (int d = 0; d < DD; ++d) {
        const float od = orow[d];
        #pragma unroll
        for (int j = 0; j < 8; ++j)
            acc[j] = fmaf(od, Wo[(size_t)d*CD + j*64 + lane], acc[j]);
    }
    #pragma unroll
    for (int j = 0; j < 8; ++j)
        out[(size_t)row*CD + j*64 + lane] = fmaxf(acc[j] + bo[j*64 + lane], 0.f);
}

// ---------------------------------------------------------------------------
extern "C" void kernel_launch(void* const* d_in, const int* in_sizes, int n_in,
                              void* d_out, int out_size, void* d_ws, size_t ws_size,
                              hipStream_t stream) {
    const float* x  = (const float*)d_in[0];
    const float* Wq = (const float*)d_in[1];
    const float* bq = (const float*)d_in[2];
    const float* Wk = (const float*)d_in[3];
    const float* bk = (const float*)d_in[4];
    const float* Wv = (const float*)d_in[5];
    const float* bv = (const float*)d_in[6];
    const float* Wo = (const float*)d_in[7];
    const float* bo = (const float*)d_in[8];
    float* out = (float*)d_out;

    // ws layout: [qh qlo kh klo vT] bf16 (2MB each = 10MB), then per-seg
    // partials o_part (nseg*4MB) + m_part/l_part (nseg*64KB each).
    // fp32 'o' (4MB) aliases qh+qlo, which are dead before reduce runs.
    ushort_t* u = (ushort_t*)d_ws;
    const size_t SEG = (size_t)NROWS * DD;  // 1048576 elems
    ushort_t* qh  = u;
    ushort_t* qlo = u + SEG;
    ushort_t* kh  = u + 2*SEG;
    ushort_t* klo = u + 3*SEG;
    ushort_t* vT  = u + 4*SEG;
    float* o      = (float*)u;              // alias qh+qlo (4MB)
    float* o_part = (float*)(u + 5*SEG);

    const size_t base_b = 5*SEG*sizeof(ushort_t);                 // 10 MB
    const size_t per_seg = (size_t)NROWS*DD*4 + (size_t)NROWS*8;  // 4MB + 128KB
    int nseg = 1;
    if      (ws_size >= base_b + 4*per_seg) nseg = 4;
    else if (ws_size >= base_b + 2*per_seg) nseg = 2;
    float* m_part = o_part + (size_t)nseg*NROWS*DD;
    float* l_part = m_part + (size_t)nseg*NROWS;

    qkv_kernel<<<1024, 256, 0, stream>>>(x, Wq, bq, Wk, bk, Wv, bv,
                                         qh, qlo, kh, klo, vT);
    attn_kernel<<<dim3(NTOK/BQ, 4, nseg), 256, 0, stream>>>(
        qh, qlo, kh, klo, vT, o_part, m_part, l_part, nseg);
    reduce_kernel<<<NROWS/4, 256, 0, stream>>>(o_part, m_part, l_part, o, nseg);
    oproj_kernel<<<NROWS/4, 256, 0, stream>>>(o, Wo, bo, out);
}

// Round 7
// 173.322 us; speedup vs baseline: 3.1103x; 1.3038x over previous
//
#include <hip/hip_runtime.h>
#include <math.h>

typedef float  f32x4   __attribute__((ext_vector_type(4)));
typedef __bf16 bf16x8  __attribute__((ext_vector_type(8)));
typedef unsigned short ushort_t;
typedef unsigned short ushort8 __attribute__((ext_vector_type(8)));

#define NTOK  4096   // H*W
#define CD    512    // C
#define DD    64     // D
#define BQ    64     // query tile (4 waves x 16 rows)
#define BK    64     // key tile
#define KSTR  72     // attn LDS row stride (bf16 elems)
#define NROWS 16384  // B*NTOK

#define MFMA(a, b, c) __builtin_amdgcn_mfma_f32_16x16x32_bf16((a), (b), (c), 0, 0, 0)

static __device__ __forceinline__ ushort_t f2bf(float f) {
    union { float f; unsigned int u; } a; a.f = f;
    unsigned int r = a.u + 0x7fffu + ((a.u >> 16) & 1u);  // RNE; finite inputs
    return (ushort_t)(r >> 16);
}
static __device__ __forceinline__ float bf2f(ushort_t h) {
    union { unsigned int u; float f; } a; a.u = ((unsigned int)h) << 16;
    return a.f;
}

// ---------------------------------------------------------------------------
// Kernel 0: weight prep (once per call, tiny). Emits transposed bf16 weights:
// wqk_hi/wqk_lo[col][k] for cols 0..127 (q cols 0-63, k cols 64-127), and
// wv_t[d][k] (plain bf16; v error is linear, not exp-amplified).
// ---------------------------------------------------------------------------
__global__ __launch_bounds__(256) void wprep_kernel(
    const float* __restrict__ Wq, const float* __restrict__ Wk,
    const float* __restrict__ Wv,
    ushort_t* __restrict__ wqk_hi, ushort_t* __restrict__ wqk_lo,
    ushort_t* __restrict__ wv_t)
{
    const int idx = blockIdx.x * 256 + threadIdx.x;   // 0 .. 192*512-1
    const int col = idx >> 9;                         // 0..191
    const int k   = idx & 511;
    const float* W = (col < 64) ? Wq : (col < 128 ? Wk : Wv);
    const int c = col & 63;
    const float wv = W[(size_t)k*DD + c];
    const ushort_t h = f2bf(wv);
    if (col < 128) {
        wqk_hi[(size_t)col*CD + k] = h;
        wqk_lo[(size_t)col*CD + k] = f2bf(wv - bf2f(h));
    } else {
        wv_t[(size_t)(col - 128)*CD + k] = h;
    }
}

// ---------------------------------------------------------------------------
// Kernel 1: QKV projection as bf16-MFMA GEMM. X (rows x 512) x W^T tiles.
// x split hi/lo in-register (fp32-grade); q,k use split W too (3 MFMAs),
// v uses plain W (2 MFMAs). 32-row tiles -> 512 blocks = 2 blocks/CU.
// Wave w: row-frag rf=w&1 (16 rows), col-group cg=w>>1 (6 of 12 col-frags;
// col-frags 0-3=q, 4-7=k, 8-11=v). Register-prefetched K loop (8 x K=64).
// Outputs: qh/qlo/kh/klo row-major, V transposed vT[b][d][tok] via LDS tile.
// ---------------------------------------------------------------------------
__global__ __launch_bounds__(256) void qkv_gemm(
    const float* __restrict__ x,
    const ushort_t* __restrict__ wqk_hi, const ushort_t* __restrict__ wqk_lo,
    const ushort_t* __restrict__ wv_t,
    const float* __restrict__ bq, const float* __restrict__ bk,
    const float* __restrict__ bv,
    ushort_t* __restrict__ qh, ushort_t* __restrict__ qlo,
    ushort_t* __restrict__ kh, ushort_t* __restrict__ klo,
    ushort_t* __restrict__ vT)
{
    __shared__ __align__(16) ushort_t xh_s [32*72];
    __shared__ __align__(16) ushort_t xl_s [32*72];
    __shared__ __align__(16) ushort_t whi_s[128*72];
    __shared__ __align__(16) ushort_t wlo_s[128*72];
    __shared__ __align__(16) ushort_t wv_s [64*72];
    __shared__ __align__(16) ushort_t vtile[64*40];   // [d][tok], pad 40 keeps b128 aligned

    const int tid  = threadIdx.x;
    const int w    = tid >> 6;
    const int lane = tid & 63;
    const int l15  = lane & 15;
    const int l4   = lane >> 4;
    const int r0   = blockIdx.x * 32;

    const int rf = w & 1;     // row fragment
    const int cg = w >> 1;    // col group (cf = 6*cg + j)

    f32x4 acc[6];
    #pragma unroll
    for (int j = 0; j < 6; ++j) acc[j] = (f32x4){0.f,0.f,0.f,0.f};

    // staging maps
    const int xrow = tid >> 3, xk = (tid & 7) * 8;    // x tile [32][64] fp32
    const int wcol = tid >> 1, wk = (tid & 1) * 32;   // wqk tile [128][64]
    const int vcol = tid >> 2, vk = (tid & 3) * 16;   // wv tile [64][64]

    f32x4   px0, px1;
    ushort8 pwh[4], pwl[4], pwv[2];

    // prologue loads (K-tile 0)
    {
        const float* xp = &x[(size_t)(r0 + xrow)*CD + xk];
        px0 = *(const f32x4*)xp;  px1 = *(const f32x4*)(xp + 4);
        const ushort_t* hp = &wqk_hi[(size_t)wcol*CD + wk];
        const ushort_t* lp = &wqk_lo[(size_t)wcol*CD + wk];
        #pragma unroll
        for (int i = 0; i < 4; ++i) {
            pwh[i] = *(const ushort8*)(hp + 8*i);
            pwl[i] = *(const ushort8*)(lp + 8*i);
        }
        const ushort_t* vp = &wv_t[(size_t)vcol*CD + vk];
        pwv[0] = *(const ushort8*)vp;  pwv[1] = *(const ushort8*)(vp + 8);
    }

    for (int kt = 0; kt < 8; ++kt) {
        __syncthreads();   // previous compute done reading LDS
        // x: convert fp32 -> hi/lo bf16 and store
        {
            ushort8 hi8, lo8;
            #pragma unroll
            for (int i = 0; i < 8; ++i) {
                const float f = (i < 4) ? px0[i] : px1[i-4];
                const ushort_t h = f2bf(f);
                hi8[i] = h;
                lo8[i] = f2bf(f - bf2f(h));
            }
            *(ushort8*)&xh_s[xrow*72 + xk] = hi8;
            *(ushort8*)&xl_s[xrow*72 + xk] = lo8;
        }
        #pragma unroll
        for (int i = 0; i < 4; ++i) {
            *(ushort8*)&whi_s[wcol*72 + wk + 8*i] = pwh[i];
            *(ushort8*)&wlo_s[wcol*72 + wk + 8*i] = pwl[i];
        }
        *(ushort8*)&wv_s[vcol*72 + vk]     = pwv[0];
        *(ushort8*)&wv_s[vcol*72 + vk + 8] = pwv[1];

        if (kt + 1 < 8) {   // prefetch next K-tile; hides under MFMA phase
            const int ko = (kt + 1) * 64;
            const float* xp = &x[(size_t)(r0 + xrow)*CD + ko + xk];
            px0 = *(const f32x4*)xp;  px1 = *(const f32x4*)(xp + 4);
            const ushort_t* hp = &wqk_hi[(size_t)wcol*CD + ko + wk];
            const ushort_t* lp = &wqk_lo[(size_t)wcol*CD + ko + wk];
            #pragma unroll
            for (int i = 0; i < 4; ++i) {
                pwh[i] = *(const ushort8*)(hp + 8*i);
                pwl[i] = *(const ushort8*)(lp + 8*i);
            }
            const ushort_t* vp = &wv_t[(size_t)vcol*CD + ko + vk];
            pwv[0] = *(const ushort8*)vp;  pwv[1] = *(const ushort8*)(vp + 8);
        }
        __syncthreads();

        // MFMA phase
        #pragma unroll
        for (int k32 = 0; k32 < 2; ++k32) {
            const int ao = (rf*16 + l15)*72 + 8*l4 + 32*k32;
            bf16x8 ah = *(const bf16x8*)&xh_s[ao];
            bf16x8 al = *(const bf16x8*)&xl_s[ao];
            #pragma unroll
            for (int j = 0; j < 6; ++j) {
                const int cf = 6*cg + j;
                if (cf < 8) {    // q or k: split W -> 3 MFMAs (fp32-grade)
                    const int bo = (16*cf + l15)*72 + 8*l4 + 32*k32;
                    bf16x8 bh = *(const bf16x8*)&whi_s[bo];
                    bf16x8 bl = *(const bf16x8*)&wlo_s[bo];
                    acc[j] = MFMA(ah, bh, acc[j]);
                    acc[j] = MFMA(al, bh, acc[j]);
                    acc[j] = MFMA(ah, bl, acc[j]);
                } else {         // v: plain W -> 2 MFMAs
                    const int bo = ((cf-8)*16 + l15)*72 + 8*l4 + 32*k32;
                    bf16x8 bv8 = *(const bf16x8*)&wv_s[bo];
                    acc[j] = MFMA(ah, bv8, acc[j]);
                    acc[j] = MFMA(al, bv8, acc[j]);
                }
            }
        }
    }

    // epilogue: bias + relu; q,k -> split bf16 global; v -> LDS tile
    #pragma unroll
    for (int j = 0; j < 6; ++j) {
        const int cf = 6*cg + j;
        const int col16 = cf*16 + l15;            // global col in [0,192)
        if (cf < 4) {
            const float bias = bq[col16];
            #pragma unroll
            for (int r = 0; r < 4; ++r) {
                const size_t row = (size_t)(r0 + rf*16 + 4*l4 + r);
                const float qv = fmaxf(acc[j][r] + bias, 0.f);
                const ushort_t h = f2bf(qv);
                qh [row*DD + col16] = h;
                qlo[row*DD + col16] = f2bf(qv - bf2f(h));
            }
        } else if (cf < 8) {
            const int kc = col16 - 64;
            const float bias = bk[kc];
            #pragma unroll
            for (int r = 0; r < 4; ++r) {
                const size_t row = (size_t)(r0 + rf*16 + 4*l4 + r);
                const float kv = fmaxf(acc[j][r] + bias, 0.f);
                const ushort_t h = f2bf(kv);
                kh [row*DD + kc] = h;
                klo[row*DD + kc] = f2bf(kv - bf2f(h));
            }
        } else {
            const int d = col16 - 128;
            const float bias = bv[d];
            #pragma unroll
            for (int r = 0; r < 4; ++r)
                vtile[d*40 + rf*16 + 4*l4 + r] =
                    f2bf(fmaxf(acc[j][r] + bias, 0.f));
        }
    }
    __syncthreads();
    // coalesced vT write: thread covers (d = tid>>2, 8 tokens at (tid&3)*8)
    {
        const int d  = tid >> 2;
        const int j8 = (tid & 3) * 8;
        const int bb   = r0 / NTOK;
        const int tok0 = r0 % NTOK;
        ushort8 vv = *(const ushort8*)&vtile[d*40 + j8];
        *(ushort8*)&vT[((size_t)bb*DD + d)*NTOK + tok0 + j8] = vv;
    }
}

// ---------------------------------------------------------------------------
// Kernel 2: flash attention over a KEY SEGMENT (split-K). Grid (N/BQ, B, nseg).
// Unchanged from round 6 (split-bf16 QK^T, fp32 register softmax, bf16 PV,
// register prefetch). Writes partial (acc, m, l); reduce_kernel combines.
// ---------------------------------------------------------------------------
__global__ __launch_bounds__(256) void attn_kernel(
    const ushort_t* __restrict__ qh, const ushort_t* __restrict__ qlo,
    const ushort_t* __restrict__ kh, const ushort_t* __restrict__ klo,
    const ushort_t* __restrict__ vT,
    float* __restrict__ o_part, float* __restrict__ m_part,
    float* __restrict__ l_part, int nseg)
{
    __shared__ __align__(16) ushort_t kh_s[BK*KSTR];
    __shared__ __align__(16) ushort_t kl_s[BK*KSTR];
    __shared__ __align__(16) ushort_t vt_s[DD*KSTR];  // [d][key]
    __shared__ __align__(16) ushort_t p_s [BQ*KSTR];  // wave-private rows

    const int tid  = threadIdx.x;
    const int w    = tid >> 6;
    const int lane = tid & 63;
    const int l15  = lane & 15;
    const int l4   = lane >> 4;
    const int b    = blockIdx.y;
    const int qb   = blockIdx.x;
    const int seg  = blockIdx.z;
    const int kv0  = seg * (NTOK / nseg);
    const int tiles = (NTOK / nseg) / BK;

    const size_t qrow = ((size_t)b*NTOK + (size_t)qb*BQ + 16*w + l15)*DD;
    bf16x8 qhf[2], qlf[2];
    qhf[0] = *(const bf16x8*)&qh [qrow + 8*l4];
    qhf[1] = *(const bf16x8*)&qh [qrow + 8*l4 + 32];
    qlf[0] = *(const bf16x8*)&qlo[qrow + 8*l4];
    qlf[1] = *(const bf16x8*)&qlo[qrow + 8*l4 + 32];

    f32x4 acc[4];
    #pragma unroll
    for (int nt = 0; nt < 4; ++nt) acc[nt] = (f32x4){0.f,0.f,0.f,0.f};
    float m_run[4] = {-INFINITY,-INFINITY,-INFINITY,-INFINITY};
    float l_run[4] = {0.f,0.f,0.f,0.f};

    const int skey = tid >> 2;
    const int sc   = (tid & 3) * 16;

    bf16x8 rg0, rg1, rg2, rg3, rg4, rg5;
    {
        const size_t kb = ((size_t)b*NTOK + kv0 + skey)*DD + sc;
        rg0 = *(const bf16x8*)&kh [kb];   rg1 = *(const bf16x8*)&kh [kb + 8];
        rg2 = *(const bf16x8*)&klo[kb];   rg3 = *(const bf16x8*)&klo[kb + 8];
        const size_t vb_ = ((size_t)b*DD + skey)*NTOK + kv0 + sc;
        rg4 = *(const bf16x8*)&vT[vb_];   rg5 = *(const bf16x8*)&vT[vb_ + 8];
    }

    for (int t = 0; t < tiles; ++t) {
        __syncthreads();
        *(bf16x8*)&kh_s[skey*KSTR + sc]     = rg0;
        *(bf16x8*)&kh_s[skey*KSTR + sc + 8] = rg1;
        *(bf16x8*)&kl_s[skey*KSTR + sc]     = rg2;
        *(bf16x8*)&kl_s[skey*KSTR + sc + 8] = rg3;
        *(bf16x8*)&vt_s[skey*KSTR + sc]     = rg4;
        *(bf16x8*)&vt_s[skey*KSTR + sc + 8] = rg5;
        if (t + 1 < tiles) {
            const size_t kb = ((size_t)b*NTOK + kv0 + (t+1)*BK + skey)*DD + sc;
            rg0 = *(const bf16x8*)&kh [kb];   rg1 = *(const bf16x8*)&kh [kb + 8];
            rg2 = *(const bf16x8*)&klo[kb];   rg3 = *(const bf16x8*)&klo[kb + 8];
            const size_t vb_ = ((size_t)b*DD + skey)*NTOK + kv0 + (t+1)*BK + sc;
            rg4 = *(const bf16x8*)&vT[vb_];   rg5 = *(const bf16x8*)&vT[vb_ + 8];
        }
        __syncthreads();

        f32x4 sv[4];
        #pragma unroll
        for (int nt = 0; nt < 4; ++nt) sv[nt] = (f32x4){0.f,0.f,0.f,0.f};
        #pragma unroll
        for (int nt = 0; nt < 4; ++nt) {
            #pragma unroll
            for (int s = 0; s < 2; ++s) {
                const int off = (16*nt + l15)*KSTR + 8*l4 + 32*s;
                bf16x8 khf = *(const bf16x8*)&kh_s[off];
                bf16x8 klf = *(const bf16x8*)&kl_s[off];
                sv[nt] = MFMA(qhf[s], khf, sv[nt]);
                sv[nt] = MFMA(qhf[s], klf, sv[nt]);
                sv[nt] = MFMA(qlf[s], khf, sv[nt]);
            }
        }

        float mnew[4], alpha[4], ssum[4];
        #pragma unroll
        for (int r = 0; r < 4; ++r) {
            float mr = fmaxf(fmaxf(sv[0][r], sv[1][r]), fmaxf(sv[2][r], sv[3][r]));
            mr = fmaxf(mr, __shfl_xor(mr, 1));
            mr = fmaxf(mr, __shfl_xor(mr, 2));
            mr = fmaxf(mr, __shfl_xor(mr, 4));
            mr = fmaxf(mr, __shfl_xor(mr, 8));
            mnew[r]  = fmaxf(m_run[r], mr);
            alpha[r] = __expf(m_run[r] - mnew[r]);
            m_run[r] = mnew[r];
            ssum[r]  = 0.f;
        }
        #pragma unroll
        for (int nt = 0; nt < 4; ++nt)
            #pragma unroll
            for (int r = 0; r < 4; ++r) {
                const float p = __expf(sv[nt][r] - mnew[r]);
                sv[nt][r] = p;
                ssum[r] += p;
            }
        #pragma unroll
        for (int r = 0; r < 4; ++r) {
            float s = ssum[r];
            s += __shfl_xor(s, 1);
            s += __shfl_xor(s, 2);
            s += __shfl_xor(s, 4);
            s += __shfl_xor(s, 8);
            l_run[r] = l_run[r]*alpha[r] + s;
        }

        #pragma unroll
        for (int nt = 0; nt < 4; ++nt)
            #pragma unroll
            for (int r = 0; r < 4; ++r)
                p_s[(16*w + 4*l4 + r)*KSTR + 16*nt + l15] = f2bf(sv[nt][r]);
        #pragma unroll
        for (int nt = 0; nt < 4; ++nt)
            #pragma unroll
            for (int r = 0; r < 4; ++r)
                acc[nt][r] *= alpha[r];

        bf16x8 paf[2];
        paf[0] = *(const bf16x8*)&p_s[(16*w + l15)*KSTR + 8*l4];
        paf[1] = *(const bf16x8*)&p_s[(16*w + l15)*KSTR + 8*l4 + 32];
        #pragma unroll
        for (int nt = 0; nt < 4; ++nt) {
            #pragma unroll
            for (int s = 0; s < 2; ++s) {
                bf16x8 vf = *(const bf16x8*)&vt_s[(16*nt + l15)*KSTR + 8*l4 + 32*s];
                acc[nt] = MFMA(paf[s], vf, acc[nt]);
            }
        }
    }

    const size_t prow0 = (size_t)(seg*4 + b)*NTOK + (size_t)qb*BQ + 16*w;
    #pragma unroll
    for (int r = 0; r < 4; ++r) {
        const size_t row = prow0 + 4*l4 + r;
        #pragma unroll
        for (int nt = 0; nt < 4; ++nt)
            o_part[row*DD + 16*nt + l15] = acc[nt][r];
        if (l15 == 0) { m_part[row] = m_run[r]; l_part[row] = l_run[r]; }
    }
}

// ---------------------------------------------------------------------------
// Kernel 2b: combine split-K partials. One wave per row (lane = d).
// ---------------------------------------------------------------------------
__global__ __launch_bounds__(256) void reduce_kernel(
    const float* __restrict__ o_part, const float* __restrict__ m_part,
    const float* __restrict__ l_part, float* __restrict__ o, int nseg)
{
    const int gr   = blockIdx.x * 4 + (threadIdx.x >> 6);
    const int lane = threadIdx.x & 63;
    float m = -INFINITY;
    for (int s = 0; s < nseg; ++s)
        m = fmaxf(m, m_part[(size_t)s*NROWS + gr]);
    float osum = 0.f, lsum = 0.f;
    for (int s = 0; s < nseg; ++s) {
        const float wgt = __expf(m_part[(size_t)s*NROWS + gr] - m);
        osum = fmaf(wgt, o_part[((size_t)s*NROWS + gr)*DD + lane], osum);
        lsum = fmaf(wgt, l_part[(size_t)s*NROWS + gr], lsum);
    }
    o[(size_t)gr*DD + lane] = osum / lsum;
}

// ---------------------------------------------------------------------------
// Kernel 3: output projection (fp32). One wave per row; lane covers 8 cols.
// ---------------------------------------------------------------------------
__global__ __launch_bounds__(256) void oproj_kernel(
    const float* __restrict__ o, const float* __restrict__ Wo,
    const float* __restrict__ bo, float* __restrict__ out)
{
    const int wave = threadIdx.x >> 6;
    const int lane = threadIdx.x & 63;
    int row = blockIdx.x * 4 + wave;
    row = __builtin_amdgcn_readfirstlane(row);
    const float* orow = o + (size_t)row * DD;

    float acc[8] = {0.f,0.f,0.f,0.f,0.f,0.f,0.f,0.f};
    #pragma unroll 4
    for (int d = 0; d < DD; ++d) {
        const float od = orow[d];
        #pragma unroll
        for (int j = 0; j < 8; ++j)
            acc[j] = fmaf(od, Wo[(size_t)d*CD + j*64 + lane], acc[j]);
    }
    #pragma unroll
    for (int j = 0; j < 8; ++j)
        out[(size_t)row*CD + j*64 + lane] = fmaxf(acc[j] + bo[j*64 + lane], 0.f);
}

// ---------------------------------------------------------------------------
extern "C" void kernel_launch(void* const* d_in, const int* in_sizes, int n_in,
                              void* d_out, int out_size, void* d_ws, size_t ws_size,
                              hipStream_t stream) {
    const float* x  = (const float*)d_in[0];
    const float* Wq = (const float*)d_in[1];
    const float* bq = (const float*)d_in[2];
    const float* Wk = (const float*)d_in[3];
    const float* bk = (const float*)d_in[4];
    const float* Wv = (const float*)d_in[5];
    const float* bv = (const float*)d_in[6];
    const float* Wo = (const float*)d_in[7];
    const float* bo = (const float*)d_in[8];
    float* out = (float*)d_out;

    // ws layout: [qh qlo kh klo vT] bf16 (2MB each), then prepped weights
    // (wqk_hi/lo 128x512, wv_t 64x512 bf16 = 448KB), then split-K partials.
    // fp32 'o' (4MB) aliases qh+qlo (dead before reduce runs).
    ushort_t* u = (ushort_t*)d_ws;
    const size_t SEG = (size_t)NROWS * DD;  // 1048576 elems
    ushort_t* qh  = u;
    ushort_t* qlo = u + SEG;
    ushort_t* kh  = u + 2*SEG;
    ushort_t* klo = u + 3*SEG;
    ushort_t* vT  = u + 4*SEG;
    float* o      = (float*)u;              // alias qh+qlo (4MB)

    ushort_t* wqk_hi = u + 5*SEG;           // 128*512
    ushort_t* wqk_lo = wqk_hi + 128*512;
    ushort_t* wv_t   = wqk_lo + 128*512;    // 64*512
    float*    o_part = (float*)(wv_t + 64*512);

    const size_t base_b  = (5*SEG + 320*512) * sizeof(ushort_t);
    const size_t per_seg = (size_t)NROWS*DD*4 + (size_t)NROWS*8;  // 4MB + 128KB
    int nseg = 1;
    if      (ws_size >= base_b + 4*per_seg) nseg = 4;
    else if (ws_size >= base_b + 2*per_seg) nseg = 2;
    float* m_part = o_part + (size_t)nseg*NROWS*DD;
    float* l_part = m_part + (size_t)nseg*NROWS;

    wprep_kernel<<<384, 256, 0, stream>>>(Wq, Wk, Wv, wqk_hi, wqk_lo, wv_t);
    qkv_gemm<<<NROWS/32, 256, 0, stream>>>(x, wqk_hi, wqk_lo, wv_t,
                                           bq, bk, bv, qh, qlo, kh, klo, vT);
    attn_kernel<<<dim3(NTOK/BQ, 4, nseg), 256, 0, stream>>>(
        qh, qlo, kh, klo, vT, o_part, m_part, l_part, nseg);
    reduce_kernel<<<NROWS/4, 256, 0, stream>>>(o_part, m_part, l_part, o, nseg);
    oproj_kernel<<<NROWS/4, 256, 0, stream>>>(o, Wo, bo, out);
}

// Round 8
// 162.111 us; speedup vs baseline: 3.3254x; 1.0692x over previous
//
#include <hip/hip_runtime.h>
#include <math.h>

typedef float  f32x4   __attribute__((ext_vector_type(4)));
typedef __bf16 bf16x8  __attribute__((ext_vector_type(8)));
typedef unsigned short ushort_t;
typedef unsigned short ushort8 __attribute__((ext_vector_type(8)));

#define NTOK  4096   // H*W
#define CD    512    // C
#define DD    64     // D
#define BQ    128    // query tile (8 waves x 16 rows)
#define BK    64     // key tile
#define KSTR  72     // attn LDS row stride (bf16 elems)
#define NROWS 16384  // B*NTOK
#define LOG2E 1.4426950408889634f

#define MFMA(a, b, c) __builtin_amdgcn_mfma_f32_16x16x32_bf16((a), (b), (c), 0, 0, 0)
#define EXP2(x) __builtin_amdgcn_exp2f(x)

static __device__ __forceinline__ ushort_t f2bf(float f) {
    union { __bf16 h; ushort_t u; } a; a.h = (__bf16)f; return a.u;
}
static __device__ __forceinline__ float bf2f(ushort_t h) {
    union { unsigned int u; float f; } a; a.u = ((unsigned int)h) << 16;
    return a.f;
}

// ---------------------------------------------------------------------------
// Kernel 0: weight prep. Transposed bf16 weights: wqk_hi/lo[col][k] for
// cols 0..127 (q=0-63 PRE-SCALED by log2e for exp2-domain softmax, k=64-127),
// wv_t[d][k] plain bf16.
// ---------------------------------------------------------------------------
__global__ __launch_bounds__(256) void wprep_kernel(
    const float* __restrict__ Wq, const float* __restrict__ Wk,
    const float* __restrict__ Wv,
    ushort_t* __restrict__ wqk_hi, ushort_t* __restrict__ wqk_lo,
    ushort_t* __restrict__ wv_t)
{
    const int idx = blockIdx.x * 256 + threadIdx.x;   // 0 .. 192*512-1
    const int col = idx >> 9;                         // 0..191
    const int k   = idx & 511;
    const float* W = (col < 64) ? Wq : (col < 128 ? Wk : Wv);
    const int c = col & 63;
    float wv = W[(size_t)k*DD + c];
    if (col < 64) wv *= LOG2E;        // q scaled: scores land in log2 domain
    const ushort_t h = f2bf(wv);
    if (col < 128) {
        wqk_hi[(size_t)col*CD + k] = h;
        wqk_lo[(size_t)col*CD + k] = f2bf(wv - bf2f(h));
    } else {
        wv_t[(size_t)(col - 128)*CD + k] = h;
    }
}

// ---------------------------------------------------------------------------
// Kernel 1: QKV projection as bf16-MFMA GEMM (unchanged structure from r6;
// hw bf16 converts). 32-row tiles, 512 blocks, register-prefetched K loop.
// ---------------------------------------------------------------------------
__global__ __launch_bounds__(256) void qkv_gemm(
    const float* __restrict__ x,
    const ushort_t* __restrict__ wqk_hi, const ushort_t* __restrict__ wqk_lo,
    const ushort_t* __restrict__ wv_t,
    const float* __restrict__ bq, const float* __restrict__ bk,
    const float* __restrict__ bv,
    ushort_t* __restrict__ qh, ushort_t* __restrict__ qlo,
    ushort_t* __restrict__ kh, ushort_t* __restrict__ klo,
    ushort_t* __restrict__ vT)
{
    __shared__ __align__(16) ushort_t xh_s [32*72];
    __shared__ __align__(16) ushort_t xl_s [32*72];
    __shared__ __align__(16) ushort_t whi_s[128*72];
    __shared__ __align__(16) ushort_t wlo_s[128*72];
    __shared__ __align__(16) ushort_t wv_s [64*72];
    __shared__ __align__(16) ushort_t vtile[64*40];

    const int tid  = threadIdx.x;
    const int w    = tid >> 6;
    const int lane = tid & 63;
    const int l15  = lane & 15;
    const int l4   = lane >> 4;
    const int r0   = blockIdx.x * 32;

    const int rf = w & 1;     // row fragment
    const int cg = w >> 1;    // col group (cf = 6*cg + j)

    f32x4 acc[6];
    #pragma unroll
    for (int j = 0; j < 6; ++j) acc[j] = (f32x4){0.f,0.f,0.f,0.f};

    const int xrow = tid >> 3, xk = (tid & 7) * 8;
    const int wcol = tid >> 1, wk = (tid & 1) * 32;
    const int vcol = tid >> 2, vk = (tid & 3) * 16;

    f32x4   px0, px1;
    ushort8 pwh[4], pwl[4], pwv[2];

    {
        const float* xp = &x[(size_t)(r0 + xrow)*CD + xk];
        px0 = *(const f32x4*)xp;  px1 = *(const f32x4*)(xp + 4);
        const ushort_t* hp = &wqk_hi[(size_t)wcol*CD + wk];
        const ushort_t* lp = &wqk_lo[(size_t)wcol*CD + wk];
        #pragma unroll
        for (int i = 0; i < 4; ++i) {
            pwh[i] = *(const ushort8*)(hp + 8*i);
            pwl[i] = *(const ushort8*)(lp + 8*i);
        }
        const ushort_t* vp = &wv_t[(size_t)vcol*CD + vk];
        pwv[0] = *(const ushort8*)vp;  pwv[1] = *(const ushort8*)(vp + 8);
    }

    for (int kt = 0; kt < 8; ++kt) {
        __syncthreads();
        {
            ushort8 hi8, lo8;
            #pragma unroll
            for (int i = 0; i < 8; ++i) {
                const float f = (i < 4) ? px0[i] : px1[i-4];
                const ushort_t h = f2bf(f);
                hi8[i] = h;
                lo8[i] = f2bf(f - bf2f(h));
            }
            *(ushort8*)&xh_s[xrow*72 + xk] = hi8;
            *(ushort8*)&xl_s[xrow*72 + xk] = lo8;
        }
        #pragma unroll
        for (int i = 0; i < 4; ++i) {
            *(ushort8*)&whi_s[wcol*72 + wk + 8*i] = pwh[i];
            *(ushort8*)&wlo_s[wcol*72 + wk + 8*i] = pwl[i];
        }
        *(ushort8*)&wv_s[vcol*72 + vk]     = pwv[0];
        *(ushort8*)&wv_s[vcol*72 + vk + 8] = pwv[1];

        if (kt + 1 < 8) {
            const int ko = (kt + 1) * 64;
            const float* xp = &x[(size_t)(r0 + xrow)*CD + ko + xk];
            px0 = *(const f32x4*)xp;  px1 = *(const f32x4*)(xp + 4);
            const ushort_t* hp = &wqk_hi[(size_t)wcol*CD + ko + wk];
            const ushort_t* lp = &wqk_lo[(size_t)wcol*CD + ko + wk];
            #pragma unroll
            for (int i = 0; i < 4; ++i) {
                pwh[i] = *(const ushort8*)(hp + 8*i);
                pwl[i] = *(const ushort8*)(lp + 8*i);
            }
            const ushort_t* vp = &wv_t[(size_t)vcol*CD + ko + vk];
            pwv[0] = *(const ushort8*)vp;  pwv[1] = *(const ushort8*)(vp + 8);
        }
        __syncthreads();

        #pragma unroll
        for (int k32 = 0; k32 < 2; ++k32) {
            const int ao = (rf*16 + l15)*72 + 8*l4 + 32*k32;
            bf16x8 ah = *(const bf16x8*)&xh_s[ao];
            bf16x8 al = *(const bf16x8*)&xl_s[ao];
            #pragma unroll
            for (int j = 0; j < 6; ++j) {
                const int cf = 6*cg + j;
                if (cf < 8) {
                    const int bo = (16*cf + l15)*72 + 8*l4 + 32*k32;
                    bf16x8 bh = *(const bf16x8*)&whi_s[bo];
                    bf16x8 bl = *(const bf16x8*)&wlo_s[bo];
                    acc[j] = MFMA(ah, bh, acc[j]);
                    acc[j] = MFMA(al, bh, acc[j]);
                    acc[j] = MFMA(ah, bl, acc[j]);
                } else {
                    const int bo = ((cf-8)*16 + l15)*72 + 8*l4 + 32*k32;
                    bf16x8 bv8 = *(const bf16x8*)&wv_s[bo];
                    acc[j] = MFMA(ah, bv8, acc[j]);
                    acc[j] = MFMA(al, bv8, acc[j]);
                }
            }
        }
    }

    #pragma unroll
    for (int j = 0; j < 6; ++j) {
        const int cf = 6*cg + j;
        const int col16 = cf*16 + l15;
        if (cf < 4) {
            const float bias = bq[col16] * LOG2E;   // q is log2e-scaled
            #pragma unroll
            for (int r = 0; r < 4; ++r) {
                const size_t row = (size_t)(r0 + rf*16 + 4*l4 + r);
                const float qv = fmaxf(acc[j][r] + bias, 0.f);
                const ushort_t h = f2bf(qv);
                qh [row*DD + col16] = h;
                qlo[row*DD + col16] = f2bf(qv - bf2f(h));
            }
        } else if (cf < 8) {
            const int kc = col16 - 64;
            const float bias = bk[kc];
            #pragma unroll
            for (int r = 0; r < 4; ++r) {
                const size_t row = (size_t)(r0 + rf*16 + 4*l4 + r);
                const float kv = fmaxf(acc[j][r] + bias, 0.f);
                const ushort_t h = f2bf(kv);
                kh [row*DD + kc] = h;
                klo[row*DD + kc] = f2bf(kv - bf2f(h));
            }
        } else {
            const int d = col16 - 128;
            const float bias = bv[d];
            #pragma unroll
            for (int r = 0; r < 4; ++r)
                vtile[d*40 + rf*16 + 4*l4 + r] =
                    f2bf(fmaxf(acc[j][r] + bias, 0.f));
        }
    }
    __syncthreads();
    {
        const int d  = tid >> 2;
        const int j8 = (tid & 3) * 8;
        const int bb   = r0 / NTOK;
        const int tok0 = r0 % NTOK;
        ushort8 vv = *(const ushort8*)&vtile[d*40 + j8];
        *(ushort8*)&vT[((size_t)bb*DD + d)*NTOK + tok0 + j8] = vv;
    }
}

// ---------------------------------------------------------------------------
// Kernel 2: flash attention, 8 waves (BQ=128), split-K over nseg segments.
// Scores already in log2 domain (q pre-scaled) -> single v_exp per element.
// Register prefetch of next K/V tile; hw cvt for P->bf16.
// ---------------------------------------------------------------------------
__global__ __launch_bounds__(512) void attn_kernel(
    const ushort_t* __restrict__ qh, const ushort_t* __restrict__ qlo,
    const ushort_t* __restrict__ kh, const ushort_t* __restrict__ klo,
    const ushort_t* __restrict__ vT,
    float* __restrict__ o_part, float* __restrict__ m_part,
    float* __restrict__ l_part, int nseg)
{
    __shared__ __align__(16) ushort_t kh_s[BK*KSTR];
    __shared__ __align__(16) ushort_t kl_s[BK*KSTR];
    __shared__ __align__(16) ushort_t vt_s[DD*KSTR];   // [d][key]
    __shared__ __align__(16) ushort_t p_s [BQ*KSTR];   // wave-private rows

    const int tid  = threadIdx.x;
    const int w    = tid >> 6;     // 0..7
    const int lane = tid & 63;
    const int l15  = lane & 15;
    const int l4   = lane >> 4;
    const int b    = blockIdx.y;
    const int qb   = blockIdx.x;
    const int seg  = blockIdx.z;
    const int kv0  = seg * (NTOK / nseg);
    const int tiles = (NTOK / nseg) / BK;

    const size_t qrow = ((size_t)b*NTOK + (size_t)qb*BQ + 16*w + l15)*DD;
    bf16x8 qhf[2], qlf[2];
    qhf[0] = *(const bf16x8*)&qh [qrow + 8*l4];
    qhf[1] = *(const bf16x8*)&qh [qrow + 8*l4 + 32];
    qlf[0] = *(const bf16x8*)&qlo[qrow + 8*l4];
    qlf[1] = *(const bf16x8*)&qlo[qrow + 8*l4 + 32];

    f32x4 acc[4];
    #pragma unroll
    for (int nt = 0; nt < 4; ++nt) acc[nt] = (f32x4){0.f,0.f,0.f,0.f};
    float m_run[4] = {-INFINITY,-INFINITY,-INFINITY,-INFINITY};
    float l_run[4] = {0.f,0.f,0.f,0.f};

    // staging: 512 thr, thread covers one b128 per buffer
    const int skey = tid >> 3;          // 0..63 (key row / d row)
    const int sc   = (tid & 7) * 8;     // col offset
    bf16x8 rgk, rgl, rgv;
    {
        const size_t kb = ((size_t)b*NTOK + kv0 + skey)*DD + sc;
        rgk = *(const bf16x8*)&kh [kb];
        rgl = *(const bf16x8*)&klo[kb];
        const size_t vb_ = ((size_t)b*DD + skey)*NTOK + kv0 + sc;
        rgv = *(const bf16x8*)&vT[vb_];
    }

    for (int t = 0; t < tiles; ++t) {
        __syncthreads();
        *(bf16x8*)&kh_s[skey*KSTR + sc] = rgk;
        *(bf16x8*)&kl_s[skey*KSTR + sc] = rgl;
        *(bf16x8*)&vt_s[skey*KSTR + sc] = rgv;
        if (t + 1 < tiles) {
            const size_t kb = ((size_t)b*NTOK + kv0 + (t+1)*BK + skey)*DD + sc;
            rgk = *(const bf16x8*)&kh [kb];
            rgl = *(const bf16x8*)&klo[kb];
            const size_t vb_ = ((size_t)b*DD + skey)*NTOK + kv0 + (t+1)*BK + sc;
            rgv = *(const bf16x8*)&vT[vb_];
        }
        __syncthreads();

        // ---- S (log2 domain) = Q K^T, split-bf16 x3 ----
        f32x4 sv[4];
        #pragma unroll
        for (int nt = 0; nt < 4; ++nt) sv[nt] = (f32x4){0.f,0.f,0.f,0.f};
        #pragma unroll
        for (int nt = 0; nt < 4; ++nt) {
            #pragma unroll
            for (int s = 0; s < 2; ++s) {
                const int off = (16*nt + l15)*KSTR + 8*l4 + 32*s;
                bf16x8 khf = *(const bf16x8*)&kh_s[off];
                bf16x8 klf = *(const bf16x8*)&kl_s[off];
                sv[nt] = MFMA(qhf[s], khf, sv[nt]);
                sv[nt] = MFMA(qhf[s], klf, sv[nt]);
                sv[nt] = MFMA(qlf[s], khf, sv[nt]);
            }
        }

        // ---- online softmax (exp2) ----
        float mnew[4], alpha[4], ssum[4];
        #pragma unroll
        for (int r = 0; r < 4; ++r) {
            float mr = fmaxf(fmaxf(sv[0][r], sv[1][r]), fmaxf(sv[2][r], sv[3][r]));
            mr = fmaxf(mr, __shfl_xor(mr, 1));
            mr = fmaxf(mr, __shfl_xor(mr, 2));
            mr = fmaxf(mr, __shfl_xor(mr, 4));
            mr = fmaxf(mr, __shfl_xor(mr, 8));
            mnew[r]  = fmaxf(m_run[r], mr);
            alpha[r] = EXP2(m_run[r] - mnew[r]);
            m_run[r] = mnew[r];
            ssum[r]  = 0.f;
        }
        #pragma unroll
        for (int nt = 0; nt < 4; ++nt)
            #pragma unroll
            for (int r = 0; r < 4; ++r) {
                const float p = EXP2(sv[nt][r] - mnew[r]);
                sv[nt][r] = p;
                ssum[r] += p;
            }
        #pragma unroll
        for (int r = 0; r < 4; ++r) {
            float s = ssum[r];
            s += __shfl_xor(s, 1);
            s += __shfl_xor(s, 2);
            s += __shfl_xor(s, 4);
            s += __shfl_xor(s, 8);
            l_run[r] = l_run[r]*alpha[r] + s;
        }

        // ---- P -> LDS (hw cvt) wave-private; rescale acc ----
        #pragma unroll
        for (int nt = 0; nt < 4; ++nt)
            #pragma unroll
            for (int r = 0; r < 4; ++r)
                p_s[(16*w + 4*l4 + r)*KSTR + 16*nt + l15] = f2bf(sv[nt][r]);
        #pragma unroll
        for (int nt = 0; nt < 4; ++nt)
            #pragma unroll
            for (int r = 0; r < 4; ++r)
                acc[nt][r] *= alpha[r];

        // ---- PV ----
        bf16x8 paf[2];
        paf[0] = *(const bf16x8*)&p_s[(16*w + l15)*KSTR + 8*l4];
        paf[1] = *(const bf16x8*)&p_s[(16*w + l15)*KSTR + 8*l4 + 32];
        #pragma unroll
        for (int nt = 0; nt < 4; ++nt) {
            #pragma unroll
            for (int s = 0; s < 2; ++s) {
                bf16x8 vf = *(const bf16x8*)&vt_s[(16*nt + l15)*KSTR + 8*l4 + 32*s];
                acc[nt] = MFMA(paf[s], vf, acc[nt]);
            }
        }
    }

    const size_t prow0 = (size_t)(seg*4 + b)*NTOK + (size_t)qb*BQ + 16*w;
    #pragma unroll
    for (int r = 0; r < 4; ++r) {
        const size_t row = prow0 + 4*l4 + r;
        #pragma unroll
        for (int nt = 0; nt < 4; ++nt)
            o_part[row*DD + 16*nt + l15] = acc[nt][r];
        if (l15 == 0) { m_part[row] = m_run[r]; l_part[row] = l_run[r]; }
    }
}

// ---------------------------------------------------------------------------
// Kernel 2b: combine split-K partials (m in log2 domain -> exp2 weights).
// ---------------------------------------------------------------------------
__global__ __launch_bounds__(256) void reduce_kernel(
    const float* __restrict__ o_part, const float* __restrict__ m_part,
    const float* __restrict__ l_part, float* __restrict__ o, int nseg)
{
    const int gr   = blockIdx.x * 4 + (threadIdx.x >> 6);
    const int lane = threadIdx.x & 63;
    float m = -INFINITY;
    for (int s = 0; s < nseg; ++s)
        m = fmaxf(m, m_part[(size_t)s*NROWS + gr]);
    float osum = 0.f, lsum = 0.f;
    for (int s = 0; s < nseg; ++s) {
        const float wgt = EXP2(m_part[(size_t)s*NROWS + gr] - m);
        osum = fmaf(wgt, o_part[((size_t)s*NROWS + gr)*DD + lane], osum);
        lsum = fmaf(wgt, l_part[(size_t)s*NROWS + gr], lsum);
    }
    o[(size_t)gr*DD + lane] = osum / lsum;
}

// ---------------------------------------------------------------------------
// Kernel 3: output projection (fp32). One wave per row; lane covers 8 cols.
// ---------------------------------------------------------------------------
__global__ __launch_bounds__(256) void oproj_kernel(
    const float* __restrict__ o, const float* __restrict__ Wo,
    const float* __restrict__ bo, float* __restrict__ out)
{
    const int wave = threadIdx.x >> 6;
    const int lane = threadIdx.x & 63;
    int row = blockIdx.x * 4 + wave;
    row = __builtin_amdgcn_readfirstlane(row);
    const float* orow = o + (size_t)row * DD;

    float acc[8] = {0.f,0.f,0.f,0.f,0.f,0.f,0.f,0.f};
    #pragma unroll 4
    for (int d = 0; d < DD; ++d) {
        const float od = orow[d];
        #pragma unroll
        for (int j = 0; j < 8; ++j)
            acc[j] = fmaf(od, Wo[(size_t)d*CD + j*64 + lane], acc[j]);
    }
    #pragma unroll
    for (int j = 0; j < 8; ++j)
        out[(size_t)row*CD + j*64 + lane] = fmaxf(acc[j] + bo[j*64 + lane], 0.f);
}

// ---------------------------------------------------------------------------
extern "C" void kernel_launch(void* const* d_in, const int* in_sizes, int n_in,
                              void* d_out, int out_size, void* d_ws, size_t ws_size,
                              hipStream_t stream) {
    const float* x  = (const float*)d_in[0];
    const float* Wq = (const float*)d_in[1];
    const float* bq = (const float*)d_in[2];
    const float* Wk = (const float*)d_in[3];
    const float* bk = (const float*)d_in[4];
    const float* Wv = (const float*)d_in[5];
    const float* bv = (const float*)d_in[6];
    const float* Wo = (const float*)d_in[7];
    const float* bo = (const float*)d_in[8];
    float* out = (float*)d_out;

    ushort_t* u = (ushort_t*)d_ws;
    const size_t SEG = (size_t)NROWS * DD;  // 1048576 elems
    ushort_t* qh  = u;
    ushort_t* qlo = u + SEG;
    ushort_t* kh  = u + 2*SEG;
    ushort_t* klo = u + 3*SEG;
    ushort_t* vT  = u + 4*SEG;
    float* o      = (float*)u;              // alias qh+qlo (dead before reduce)

    ushort_t* wqk_hi = u + 5*SEG;           // 128*512
    ushort_t* wqk_lo = wqk_hi + 128*512;
    ushort_t* wv_t   = wqk_lo + 128*512;    // 64*512
    float*    o_part = (float*)(wv_t + 64*512);

    const size_t base_b  = (5*SEG + 320*512) * sizeof(ushort_t);
    const size_t per_seg = (size_t)NROWS*DD*4 + (size_t)NROWS*8;
    int nseg = 1;
    if      (ws_size >= base_b + 4*per_seg) nseg = 4;
    else if (ws_size >= base_b + 2*per_seg) nseg = 2;
    float* m_part = o_part + (size_t)nseg*NROWS*DD;
    float* l_part = m_part + (size_t)nseg*NROWS;

    wprep_kernel<<<384, 256, 0, stream>>>(Wq, Wk, Wv, wqk_hi, wqk_lo, wv_t);
    qkv_gemm<<<NROWS/32, 256, 0, stream>>>(x, wqk_hi, wqk_lo, wv_t,
                                           bq, bk, bv, qh, qlo, kh, klo, vT);
    attn_kernel<<<dim3(NTOK/BQ, 4, nseg), 512, 0, stream>>>(
        qh, qlo, kh, klo, vT, o_part, m_part, l_part, nseg);
    reduce_kernel<<<NROWS/4, 256, 0, stream>>>(o_part, m_part, l_part, o, nseg);
    oproj_kernel<<<NROWS/4, 256, 0, stream>>>(o, Wo, bo, out);
}

// Round 9
// 112.646 us; speedup vs baseline: 4.7856x; 1.4391x over previous
//
#include <hip/hip_runtime.h>
#include <math.h>

typedef float  f32x4   __attribute__((ext_vector_type(4)));
typedef __bf16 bf16x8  __attribute__((ext_vector_type(8)));
typedef unsigned short ushort_t;
typedef unsigned short ushort8 __attribute__((ext_vector_type(8)));

#define NTOK  4096   // H*W
#define CD    512    // C
#define DD    64     // D
#define BQ    128    // query tile (8 waves x 16 rows)
#define BK    64     // key tile
#define KSTR  72     // attn LDS row stride (bf16 elems)
#define NROWS 16384  // B*NTOK
#define LOG2E 1.4426950408889634f

#define MFMA(a, b, c) __builtin_amdgcn_mfma_f32_16x16x32_bf16((a), (b), (c), 0, 0, 0)
#define EXP2(x) __builtin_amdgcn_exp2f(x)

static __device__ __forceinline__ ushort_t f2bf(float f) {
    union { __bf16 h; ushort_t u; } a; a.h = (__bf16)f; return a.u;
}
static __device__ __forceinline__ float bf2f(ushort_t h) {
    union { unsigned int u; float f; } a; a.u = ((unsigned int)h) << 16;
    return a.f;
}

// ---------------------------------------------------------------------------
// Kernel 0: weight prep. wqk_hi/lo[col][k] cols 0..127 (q=0-63 log2e-scaled,
// k=64-127), wv_t[d][k], and woT[c][d] (Wo transposed, plain bf16).
// ---------------------------------------------------------------------------
__global__ __launch_bounds__(256) void wprep_kernel(
    const float* __restrict__ Wq, const float* __restrict__ Wk,
    const float* __restrict__ Wv, const float* __restrict__ Wo,
    ushort_t* __restrict__ wqk_hi, ushort_t* __restrict__ wqk_lo,
    ushort_t* __restrict__ wv_t, ushort_t* __restrict__ woT)
{
    const int idx = blockIdx.x * 256 + threadIdx.x;   // 0 .. 131071
    if (idx < 192*512) {
        const int col = idx >> 9;                     // 0..191
        const int k   = idx & 511;
        const float* W = (col < 64) ? Wq : (col < 128 ? Wk : Wv);
        const int c = col & 63;
        float wv = W[(size_t)k*DD + c];
        if (col < 64) wv *= LOG2E;    // q scaled: scores in log2 domain
        const ushort_t h = f2bf(wv);
        if (col < 128) {
            wqk_hi[(size_t)col*CD + k] = h;
            wqk_lo[(size_t)col*CD + k] = f2bf(wv - bf2f(h));
        } else {
            wv_t[(size_t)(col - 128)*CD + k] = h;
        }
    } else {
        const int i = idx - 192*512;                  // 0 .. 32767
        const int c = i >> 6, d = i & 63;
        woT[i] = f2bf(Wo[(size_t)d*CD + c]);
    }
}

// ---------------------------------------------------------------------------
// Kernel 1: QKV projection as bf16-MFMA GEMM (unchanged from r7).
// ---------------------------------------------------------------------------
__global__ __launch_bounds__(256) void qkv_gemm(
    const float* __restrict__ x,
    const ushort_t* __restrict__ wqk_hi, const ushort_t* __restrict__ wqk_lo,
    const ushort_t* __restrict__ wv_t,
    const float* __restrict__ bq, const float* __restrict__ bk,
    const float* __restrict__ bv,
    ushort_t* __restrict__ qh, ushort_t* __restrict__ qlo,
    ushort_t* __restrict__ kh, ushort_t* __restrict__ klo,
    ushort_t* __restrict__ vT)
{
    __shared__ __align__(16) ushort_t xh_s [32*72];
    __shared__ __align__(16) ushort_t xl_s [32*72];
    __shared__ __align__(16) ushort_t whi_s[128*72];
    __shared__ __align__(16) ushort_t wlo_s[128*72];
    __shared__ __align__(16) ushort_t wv_s [64*72];
    __shared__ __align__(16) ushort_t vtile[64*40];

    const int tid  = threadIdx.x;
    const int w    = tid >> 6;
    const int lane = tid & 63;
    const int l15  = lane & 15;
    const int l4   = lane >> 4;
    const int r0   = blockIdx.x * 32;

    const int rf = w & 1;
    const int cg = w >> 1;

    f32x4 acc[6];
    #pragma unroll
    for (int j = 0; j < 6; ++j) acc[j] = (f32x4){0.f,0.f,0.f,0.f};

    const int xrow = tid >> 3, xk = (tid & 7) * 8;
    const int wcol = tid >> 1, wk = (tid & 1) * 32;
    const int vcol = tid >> 2, vk = (tid & 3) * 16;

    f32x4   px0, px1;
    ushort8 pwh[4], pwl[4], pwv[2];

    {
        const float* xp = &x[(size_t)(r0 + xrow)*CD + xk];
        px0 = *(const f32x4*)xp;  px1 = *(const f32x4*)(xp + 4);
        const ushort_t* hp = &wqk_hi[(size_t)wcol*CD + wk];
        const ushort_t* lp = &wqk_lo[(size_t)wcol*CD + wk];
        #pragma unroll
        for (int i = 0; i < 4; ++i) {
            pwh[i] = *(const ushort8*)(hp + 8*i);
            pwl[i] = *(const ushort8*)(lp + 8*i);
        }
        const ushort_t* vp = &wv_t[(size_t)vcol*CD + vk];
        pwv[0] = *(const ushort8*)vp;  pwv[1] = *(const ushort8*)(vp + 8);
    }

    for (int kt = 0; kt < 8; ++kt) {
        __syncthreads();
        {
            ushort8 hi8, lo8;
            #pragma unroll
            for (int i = 0; i < 8; ++i) {
                const float f = (i < 4) ? px0[i] : px1[i-4];
                const ushort_t h = f2bf(f);
                hi8[i] = h;
                lo8[i] = f2bf(f - bf2f(h));
            }
            *(ushort8*)&xh_s[xrow*72 + xk] = hi8;
            *(ushort8*)&xl_s[xrow*72 + xk] = lo8;
        }
        #pragma unroll
        for (int i = 0; i < 4; ++i) {
            *(ushort8*)&whi_s[wcol*72 + wk + 8*i] = pwh[i];
            *(ushort8*)&wlo_s[wcol*72 + wk + 8*i] = pwl[i];
        }
        *(ushort8*)&wv_s[vcol*72 + vk]     = pwv[0];
        *(ushort8*)&wv_s[vcol*72 + vk + 8] = pwv[1];

        if (kt + 1 < 8) {
            const int ko = (kt + 1) * 64;
            const float* xp = &x[(size_t)(r0 + xrow)*CD + ko + xk];
            px0 = *(const f32x4*)xp;  px1 = *(const f32x4*)(xp + 4);
            const ushort_t* hp = &wqk_hi[(size_t)wcol*CD + ko + wk];
            const ushort_t* lp = &wqk_lo[(size_t)wcol*CD + ko + wk];
            #pragma unroll
            for (int i = 0; i < 4; ++i) {
                pwh[i] = *(const ushort8*)(hp + 8*i);
                pwl[i] = *(const ushort8*)(lp + 8*i);
            }
            const ushort_t* vp = &wv_t[(size_t)vcol*CD + ko + vk];
            pwv[0] = *(const ushort8*)vp;  pwv[1] = *(const ushort8*)(vp + 8);
        }
        __syncthreads();

        #pragma unroll
        for (int k32 = 0; k32 < 2; ++k32) {
            const int ao = (rf*16 + l15)*72 + 8*l4 + 32*k32;
            bf16x8 ah = *(const bf16x8*)&xh_s[ao];
            bf16x8 al = *(const bf16x8*)&xl_s[ao];
            #pragma unroll
            for (int j = 0; j < 6; ++j) {
                const int cf = 6*cg + j;
                if (cf < 8) {
                    const int bo = (16*cf + l15)*72 + 8*l4 + 32*k32;
                    bf16x8 bh = *(const bf16x8*)&whi_s[bo];
                    bf16x8 bl = *(const bf16x8*)&wlo_s[bo];
                    acc[j] = MFMA(ah, bh, acc[j]);
                    acc[j] = MFMA(al, bh, acc[j]);
                    acc[j] = MFMA(ah, bl, acc[j]);
                } else {
                    const int bo = ((cf-8)*16 + l15)*72 + 8*l4 + 32*k32;
                    bf16x8 bv8 = *(const bf16x8*)&wv_s[bo];
                    acc[j] = MFMA(ah, bv8, acc[j]);
                    acc[j] = MFMA(al, bv8, acc[j]);
                }
            }
        }
    }

    #pragma unroll
    for (int j = 0; j < 6; ++j) {
        const int cf = 6*cg + j;
        const int col16 = cf*16 + l15;
        if (cf < 4) {
            const float bias = bq[col16] * LOG2E;
            #pragma unroll
            for (int r = 0; r < 4; ++r) {
                const size_t row = (size_t)(r0 + rf*16 + 4*l4 + r);
                const float qv = fmaxf(acc[j][r] + bias, 0.f);
                const ushort_t h = f2bf(qv);
                qh [row*DD + col16] = h;
                qlo[row*DD + col16] = f2bf(qv - bf2f(h));
            }
        } else if (cf < 8) {
            const int kc = col16 - 64;
            const float bias = bk[kc];
            #pragma unroll
            for (int r = 0; r < 4; ++r) {
                const size_t row = (size_t)(r0 + rf*16 + 4*l4 + r);
                const float kv = fmaxf(acc[j][r] + bias, 0.f);
                const ushort_t h = f2bf(kv);
                kh [row*DD + kc] = h;
                klo[row*DD + kc] = f2bf(kv - bf2f(h));
            }
        } else {
            const int d = col16 - 128;
            const float bias = bv[d];
            #pragma unroll
            for (int r = 0; r < 4; ++r)
                vtile[d*40 + rf*16 + 4*l4 + r] =
                    f2bf(fmaxf(acc[j][r] + bias, 0.f));
        }
    }
    __syncthreads();
    {
        const int d  = tid >> 2;
        const int j8 = (tid & 3) * 8;
        const int bb   = r0 / NTOK;
        const int tok0 = r0 % NTOK;
        ushort8 vv = *(const ushort8*)&vtile[d*40 + j8];
        *(ushort8*)&vT[((size_t)bb*DD + d)*NTOK + tok0 + j8] = vv;
    }
}

// ---------------------------------------------------------------------------
// Kernel 2: flash attention (unchanged from r8): 8 waves, BQ=128, split-K,
// exp2-domain softmax, register prefetch.
// ---------------------------------------------------------------------------
__global__ __launch_bounds__(512) void attn_kernel(
    const ushort_t* __restrict__ qh, const ushort_t* __restrict__ qlo,
    const ushort_t* __restrict__ kh, const ushort_t* __restrict__ klo,
    const ushort_t* __restrict__ vT,
    float* __restrict__ o_part, float* __restrict__ m_part,
    float* __restrict__ l_part, int nseg)
{
    __shared__ __align__(16) ushort_t kh_s[BK*KSTR];
    __shared__ __align__(16) ushort_t kl_s[BK*KSTR];
    __shared__ __align__(16) ushort_t vt_s[DD*KSTR];
    __shared__ __align__(16) ushort_t p_s [BQ*KSTR];

    const int tid  = threadIdx.x;
    const int w    = tid >> 6;
    const int lane = tid & 63;
    const int l15  = lane & 15;
    const int l4   = lane >> 4;
    const int b    = blockIdx.y;
    const int qb   = blockIdx.x;
    const int seg  = blockIdx.z;
    const int kv0  = seg * (NTOK / nseg);
    const int tiles = (NTOK / nseg) / BK;

    const size_t qrow = ((size_t)b*NTOK + (size_t)qb*BQ + 16*w + l15)*DD;
    bf16x8 qhf[2], qlf[2];
    qhf[0] = *(const bf16x8*)&qh [qrow + 8*l4];
    qhf[1] = *(const bf16x8*)&qh [qrow + 8*l4 + 32];
    qlf[0] = *(const bf16x8*)&qlo[qrow + 8*l4];
    qlf[1] = *(const bf16x8*)&qlo[qrow + 8*l4 + 32];

    f32x4 acc[4];
    #pragma unroll
    for (int nt = 0; nt < 4; ++nt) acc[nt] = (f32x4){0.f,0.f,0.f,0.f};
    float m_run[4] = {-INFINITY,-INFINITY,-INFINITY,-INFINITY};
    float l_run[4] = {0.f,0.f,0.f,0.f};

    const int skey = tid >> 3;
    const int sc   = (tid & 7) * 8;
    bf16x8 rgk, rgl, rgv;
    {
        const size_t kb = ((size_t)b*NTOK + kv0 + skey)*DD + sc;
        rgk = *(const bf16x8*)&kh [kb];
        rgl = *(const bf16x8*)&klo[kb];
        const size_t vb_ = ((size_t)b*DD + skey)*NTOK + kv0 + sc;
        rgv = *(const bf16x8*)&vT[vb_];
    }

    for (int t = 0; t < tiles; ++t) {
        __syncthreads();
        *(bf16x8*)&kh_s[skey*KSTR + sc] = rgk;
        *(bf16x8*)&kl_s[skey*KSTR + sc] = rgl;
        *(bf16x8*)&vt_s[skey*KSTR + sc] = rgv;
        if (t + 1 < tiles) {
            const size_t kb = ((size_t)b*NTOK + kv0 + (t+1)*BK + skey)*DD + sc;
            rgk = *(const bf16x8*)&kh [kb];
            rgl = *(const bf16x8*)&klo[kb];
            const size_t vb_ = ((size_t)b*DD + skey)*NTOK + kv0 + (t+1)*BK + sc;
            rgv = *(const bf16x8*)&vT[vb_];
        }
        __syncthreads();

        f32x4 sv[4];
        #pragma unroll
        for (int nt = 0; nt < 4; ++nt) sv[nt] = (f32x4){0.f,0.f,0.f,0.f};
        #pragma unroll
        for (int nt = 0; nt < 4; ++nt) {
            #pragma unroll
            for (int s = 0; s < 2; ++s) {
                const int off = (16*nt + l15)*KSTR + 8*l4 + 32*s;
                bf16x8 khf = *(const bf16x8*)&kh_s[off];
                bf16x8 klf = *(const bf16x8*)&kl_s[off];
                sv[nt] = MFMA(qhf[s], khf, sv[nt]);
                sv[nt] = MFMA(qhf[s], klf, sv[nt]);
                sv[nt] = MFMA(qlf[s], khf, sv[nt]);
            }
        }

        float mnew[4], alpha[4], ssum[4];
        #pragma unroll
        for (int r = 0; r < 4; ++r) {
            float mr = fmaxf(fmaxf(sv[0][r], sv[1][r]), fmaxf(sv[2][r], sv[3][r]));
            mr = fmaxf(mr, __shfl_xor(mr, 1));
            mr = fmaxf(mr, __shfl_xor(mr, 2));
            mr = fmaxf(mr, __shfl_xor(mr, 4));
            mr = fmaxf(mr, __shfl_xor(mr, 8));
            mnew[r]  = fmaxf(m_run[r], mr);
            alpha[r] = EXP2(m_run[r] - mnew[r]);
            m_run[r] = mnew[r];
            ssum[r]  = 0.f;
        }
        #pragma unroll
        for (int nt = 0; nt < 4; ++nt)
            #pragma unroll
            for (int r = 0; r < 4; ++r) {
                const float p = EXP2(sv[nt][r] - mnew[r]);
                sv[nt][r] = p;
                ssum[r] += p;
            }
        #pragma unroll
        for (int r = 0; r < 4; ++r) {
            float s = ssum[r];
            s += __shfl_xor(s, 1);
            s += __shfl_xor(s, 2);
            s += __shfl_xor(s, 4);
            s += __shfl_xor(s, 8);
            l_run[r] = l_run[r]*alpha[r] + s;
        }

        #pragma unroll
        for (int nt = 0; nt < 4; ++nt)
            #pragma unroll
            for (int r = 0; r < 4; ++r)
                p_s[(16*w + 4*l4 + r)*KSTR + 16*nt + l15] = f2bf(sv[nt][r]);
        #pragma unroll
        for (int nt = 0; nt < 4; ++nt)
            #pragma unroll
            for (int r = 0; r < 4; ++r)
                acc[nt][r] *= alpha[r];

        bf16x8 paf[2];
        paf[0] = *(const bf16x8*)&p_s[(16*w + l15)*KSTR + 8*l4];
        paf[1] = *(const bf16x8*)&p_s[(16*w + l15)*KSTR + 8*l4 + 32];
        #pragma unroll
        for (int nt = 0; nt < 4; ++nt) {
            #pragma unroll
            for (int s = 0; s < 2; ++s) {
                bf16x8 vf = *(const bf16x8*)&vt_s[(16*nt + l15)*KSTR + 8*l4 + 32*s];
                acc[nt] = MFMA(paf[s], vf, acc[nt]);
            }
        }
    }

    const size_t prow0 = (size_t)(seg*4 + b)*NTOK + (size_t)qb*BQ + 16*w;
    #pragma unroll
    for (int r = 0; r < 4; ++r) {
        const size_t row = prow0 + 4*l4 + r;
        #pragma unroll
        for (int nt = 0; nt < 4; ++nt)
            o_part[row*DD + 16*nt + l15] = acc[nt][r];
        if (l15 == 0) { m_part[row] = m_run[r]; l_part[row] = l_run[r]; }
    }
}

// ---------------------------------------------------------------------------
// Kernel 3: output projection as bf16-MFMA GEMM with FUSED split-K reduce.
// out = relu((softmax-combined o) @ Wo + bo). Block 256 thr = 4 waves,
// 32-row tile, all 512 cols. A-frag built in-register from o_part/m/l
// (hi/lo split bf16); B-frags (woT) read from L2. No LDS.
// ---------------------------------------------------------------------------
__global__ __launch_bounds__(256) void oproj_gemm(
    const float* __restrict__ o_part, const float* __restrict__ m_part,
    const float* __restrict__ l_part, const ushort_t* __restrict__ woT,
    const float* __restrict__ bo, float* __restrict__ out, int nseg)
{
    const int tid  = threadIdx.x;
    const int w    = tid >> 6;
    const int lane = tid & 63;
    const int l15  = lane & 15;
    const int l4   = lane >> 4;
    const int r0   = blockIdx.x * 32;
    const int rf   = w & 1;     // row fragment (16 rows)
    const int cg   = w >> 1;    // col group: cf = cg*16 + j

    // fused reduce scalars for this lane's A-row
    const int row = r0 + rf*16 + l15;
    float m = -INFINITY;
    for (int s = 0; s < nseg; ++s)
        m = fmaxf(m, m_part[(size_t)s*NROWS + row]);
    float lsum = 0.f;
    for (int s = 0; s < nseg; ++s)
        lsum = fmaf(EXP2(m_part[(size_t)s*NROWS + row] - m),
                    l_part[(size_t)s*NROWS + row], lsum);
    const float inv = 1.0f / lsum;

    f32x4 acc[16];
    #pragma unroll
    for (int j = 0; j < 16; ++j) acc[j] = (f32x4){0.f,0.f,0.f,0.f};

    #pragma unroll
    for (int ks = 0; ks < 2; ++ks) {
        const int k0 = 8*l4 + 32*ks;
        // A fragment: weighted-sum o_part across segments, normalize
        float ov[8] = {0.f,0.f,0.f,0.f,0.f,0.f,0.f,0.f};
        for (int s = 0; s < nseg; ++s) {
            const float wgt = EXP2(m_part[(size_t)s*NROWS + row] - m);
            const float* op = &o_part[((size_t)s*NROWS + row)*DD + k0];
            const f32x4 a0 = *(const f32x4*)op;
            const f32x4 a1 = *(const f32x4*)(op + 4);
            #pragma unroll
            for (int i = 0; i < 4; ++i) {
                ov[i]   = fmaf(wgt, a0[i], ov[i]);
                ov[i+4] = fmaf(wgt, a1[i], ov[i+4]);
            }
        }
        bf16x8 ah, al;
        #pragma unroll
        for (int i = 0; i < 8; ++i) {
            const float f = ov[i] * inv;
            ah[i] = (__bf16)f;
            al[i] = (__bf16)(f - (float)ah[i]);
        }
        // B fragments from L2; 2 MFMAs per col-frag (split-A x plain-B)
        #pragma unroll
        for (int j = 0; j < 16; ++j) {
            const int cf = cg*16 + j;
            const bf16x8 bfr = *(const bf16x8*)&woT[(size_t)(16*cf + l15)*DD + k0];
            acc[j] = MFMA(ah, bfr, acc[j]);
            acc[j] = MFMA(al, bfr, acc[j]);
        }
    }

    // epilogue: bias + relu, fp32 stores
    #pragma unroll
    for (int j = 0; j < 16; ++j) {
        const int col  = (cg*16 + j)*16 + l15;
        const float bias = bo[col];
        #pragma unroll
        for (int r = 0; r < 4; ++r)
            out[(size_t)(r0 + rf*16 + 4*l4 + r)*CD + col] =
                fmaxf(acc[j][r] + bias, 0.f);
    }
}

// ---------------------------------------------------------------------------
extern "C" void kernel_launch(void* const* d_in, const int* in_sizes, int n_in,
                              void* d_out, int out_size, void* d_ws, size_t ws_size,
                              hipStream_t stream) {
    const float* x  = (const float*)d_in[0];
    const float* Wq = (const float*)d_in[1];
    const float* bq = (const float*)d_in[2];
    const float* Wk = (const float*)d_in[3];
    const float* bk = (const float*)d_in[4];
    const float* Wv = (const float*)d_in[5];
    const float* bv = (const float*)d_in[6];
    const float* Wo = (const float*)d_in[7];
    const float* bo = (const float*)d_in[8];
    float* out = (float*)d_out;

    ushort_t* u = (ushort_t*)d_ws;
    const size_t SEG = (size_t)NROWS * DD;  // 1048576 elems
    ushort_t* qh  = u;
    ushort_t* qlo = u + SEG;
    ushort_t* kh  = u + 2*SEG;
    ushort_t* klo = u + 3*SEG;
    ushort_t* vT  = u + 4*SEG;

    ushort_t* wqk_hi = u + 5*SEG;           // 128*512
    ushort_t* wqk_lo = wqk_hi + 128*512;
    ushort_t* wv_t   = wqk_lo + 128*512;    // 64*512
    ushort_t* woT    = wv_t + 64*512;       // 512*64
    float*    o_part = (float*)(woT + 512*64);

    const size_t base_b  = (5*SEG + 320*512 + 512*64) * sizeof(ushort_t);
    const size_t per_seg = (size_t)NROWS*DD*4 + (size_t)NROWS*8;  // 4MB+128KB
    int nseg = 1;
    if      (ws_size >= base_b + 4*per_seg) nseg = 4;
    else if (ws_size >= base_b + 2*per_seg) nseg = 2;
    float* m_part = o_part + (size_t)nseg*NROWS*DD;
    float* l_part = m_part + (size_t)nseg*NROWS;

    wprep_kernel<<<512, 256, 0, stream>>>(Wq, Wk, Wv, Wo,
                                          wqk_hi, wqk_lo, wv_t, woT);
    qkv_gemm<<<NROWS/32, 256, 0, stream>>>(x, wqk_hi, wqk_lo, wv_t,
                                           bq, bk, bv, qh, qlo, kh, klo, vT);
    attn_kernel<<<dim3(NTOK/BQ, 4, nseg), 512, 0, stream>>>(
        qh, qlo, kh, klo, vT, o_part, m_part, l_part, nseg);
    oproj_gemm<<<NROWS/32, 256, 0, stream>>>(o_part, m_part, l_part, woT,
                                             bo, out, nseg);
}